// Round 14
// baseline (264.629 us; speedup 1.0000x reference)
//
#include <hip/hip_runtime.h>
#include <hip/hip_bf16.h>

typedef __attribute__((ext_vector_type(8))) short bf16x8;
typedef __attribute__((ext_vector_type(4))) float f32x4;

__device__ __forceinline__ float sigmoidf_(float x){ return 1.0f/(1.0f+__expf(-x)); }
__device__ __forceinline__ float tanhf_(float x){ return 1.0f - 2.0f/(1.0f+__expf(2.0f*x)); }
__device__ __forceinline__ unsigned short f2bf(float f){
    __hip_bfloat16 b = __float2bfloat16(f);
    return *reinterpret_cast<unsigned short*>(&b);
}
__device__ __forceinline__ float bf2f(unsigned short u){
    __hip_bfloat16 b = *reinterpret_cast<__hip_bfloat16*>(&u);
    return __bfloat162float(b);
}

// ---------------------------------------------------------------------------
// Layouts (unchanged — verified correct):
//  Bg (ushort): 68 slabs of 21504 ush; slab = [plane hi/lo][21 slots][4 qr][16 j][8 e];
//   plane stride 10752 ush (= 21504 B = 1344 float4).
//   Slabs 0..63  = per-o ks0: kk<18 -> W_ih[gate][100+kk]; kk==18 -> bias row
//     (b_ih(+b_hh for r/z) + obs.W_ih[:, :100]); A supplies 1.0 at k=18.
//   Slabs 64..67 = H ksteps 1..4 of W_hh. Slots 0..13 -> tiles 0..13 (r,z);
//     slots 14..20 -> tiles 21..27 (hn). REGION 3 (hn) uses gate rows 200+u!
//   A wave's per-slot read = 64 consecutive 16-B chunks = 1 KB coalesced, so
//   B is read DIRECTLY from global/L2 — no LDS, no barriers in gru_level.
//  h (float32): [rows][128]; cols 112..127 zeroed explicitly.
// ---------------------------------------------------------------------------
__global__ __launch_bounds__(64) void precompute_kernel(
    const float* __restrict__ obs, const float* __restrict__ W_ih,
    const float* __restrict__ W_hh, const float* __restrict__ b_ih,
    const float* __restrict__ b_hh, const float* __restrict__ W1,
    const float* __restrict__ W2,
    unsigned short* __restrict__ Bg,
    float* __restrict__ W1T, float* __restrict__ W2T)
{
    int t = blockIdx.x * 64 + threadIdx.x;
    if (t < 688128) { // ks0 slabs, one per o: 64 * 10752 positions (per plane)
        int o = t / 10752, r = t % 10752;
        int s = r / 512, r2 = r % 512;
        int j = r2 / 32, kk = r2 % 32;
        int region = s / 7;                 // 0=r,1=z,2=i_n
        int u = (s % 7) * 16 + j;
        float wv = 0.f;
        if (u < 100) {
            int gate = region * 100 + u;
            if (kk < 18) {
                wv = W_ih[(size_t)gate * 118 + 100 + kk];
            } else if (kk == 18) { // bias row
                wv = b_ih[gate] + (region < 2 ? b_hh[gate] : 0.f);
                const float* orow = obs + o * 100;
                const float* wrow = W_ih + (size_t)gate * 118;
                for (int k = 0; k < 100; ++k) wv = fmaf(orow[k], wrow[k], wv);
            }
        }
        unsigned short h = f2bf(wv);
        unsigned short l = f2bf(wv - bf2f(h));
        int qr = kk >> 3, e = kk & 7;
        size_t base = (size_t)o * 21504 + (size_t)((s * 4 + qr) * 16 + j) * 8 + e;
        Bg[base] = h;
        Bg[base + 10752] = l;
        return;
    }
    t -= 688128;
    if (t < 43008) { // H slabs (ks 1..4): 4 * 10752 positions
        int ks = 1 + t / 10752, r = t % 10752;
        int s = r / 512, r2 = r % 512;
        int j = r2 / 32, kk = r2 % 32;
        int tt = (s < 14) ? s : s + 7;
        int region = tt / 7;
        int u = (tt % 7) * 16 + j;
        float wv = 0.f;
        if (u < 100) {
            // region 3 (h_n) uses the SAME n-gate rows (200+u) as region 2
            int gate = (region == 3 ? 2 : region) * 100 + u;
            int kh = (ks - 1) * 32 + kk;
            if (kh < 100) wv = W_hh[(size_t)gate * 100 + kh];
        }
        unsigned short h = f2bf(wv);
        unsigned short l = f2bf(wv - bf2f(h));
        int qr = kk >> 3, e = kk & 7;
        size_t base = (size_t)(64 + ks - 1) * 21504
                    + (size_t)((s * 4 + qr) * 16 + j) * 8 + e;
        Bg[base] = h;
        Bg[base + 10752] = l;
        return;
    }
    t -= 43008;
    if (t < 5000) { int g = t / 50, j = t % 50; W1T[t] = W1[j * 100 + g]; return; }
    t -= 5000;
    if (t < 1250) { int j = t / 25, i = t % 25; W2T[t] = W2[i * 50 + j]; }
}

// ---------------------------------------------------------------------------
// GRU level via MFMA — BARRIER-FREE. Wave = one 16-cell M-tile; B fragments
// are read directly from global (L2-resident, 1 KB coalesced per slot); no
// __shared__, no __syncthreads. Per-acc MFMA order (hi*bhi, lo*bhi, hi*blo)
// identical to all previous rounds -> bit-identical results.
// Bijective XCD swizzle clusters same-o blocks per XCD L2 (grids % 8 == 0).
// ---------------------------------------------------------------------------
template<bool HASH, int NW>
__global__ __launch_bounds__(NW * 64) void gru_level(
    const unsigned short* __restrict__ Bg,  // 68 slabs (see layout)
    const float* __restrict__ bhh,          // b_hh (for h_n bias rows 200+u)
    const float* __restrict__ samp,         // (O,P,63,8)
    const float* __restrict__ addr,         // (O,P,63,10)
    const float* __restrict__ hin,          // [cellsIn][128] f32
    float* __restrict__ hout,               // [rowsOut][128] f32
    int lw, int last)
{
    const int tid = threadIdx.x;
    const int lane = tid & 63;
    const int wid = tid >> 6;
    const int j15 = lane & 15;
    const int qr = lane >> 4;
    // XCD swizzle: consecutive work indices land on the same XCD (grid % 8 == 0)
    const int wk = (blockIdx.x & 7) * (gridDim.x >> 3) + (blockIdx.x >> 3);
    const int c0 = wk * (NW * 16);
    const int c0w = c0 + wid * 16;
    const int o = c0w >> (lw + 6);          // uniform per wave

    f32x4 acc[28];
    #pragma unroll
    for (int t = 0; t < 28; ++t) acc[t] = (f32x4){0.f, 0.f, 0.f, 0.f};

    const int w = 1 << lw;
    const int cm = c0w + j15;
    const int opm = cm >> lw;
    const int nodem = w - 1 + (cm & (w - 1));
    const size_t nb = (size_t)opm * 63 + nodem;
    float xv0=0.f,xv1=0.f,xv2=0.f,xv3=0.f,xv4=0.f,xv5=0.f,xv6=0.f,xv7=0.f;
    if (qr == 0) {
        const float4* s4 = (const float4*)(samp + nb * 8);
        float4 a = s4[0], b = s4[1];
        xv0=a.x; xv1=a.y; xv2=a.z; xv3=a.w; xv4=b.x; xv5=b.y; xv6=b.z; xv7=b.w;
    } else if (qr == 1) {
        const float2* a2 = (const float2*)(addr + nb * 10);
        float2 e0=a2[0], e1=a2[1], e2=a2[2], e3=a2[3];
        xv0=e0.x; xv1=e0.y; xv2=e1.x; xv3=e1.y; xv4=e2.x; xv5=e2.y; xv6=e3.x; xv7=e3.y;
    } else if (qr == 2) {
        xv0 = addr[nb * 10 + 8]; xv1 = addr[nb * 10 + 9];
        xv2 = 1.0f;                          // bias row k=18
    }
    bf16x8 axhi, axlo;
    #define CVT(e, val) { unsigned short hh = f2bf(val); \
        axhi[e] = (short)hh; axlo[e] = (short)f2bf((val) - bf2f(hh)); }
    CVT(0, xv0) CVT(1, xv1) CVT(2, xv2) CVT(3, xv3)
    CVT(4, xv4) CVT(5, xv5) CVT(6, xv6) CVT(7, xv7)
    #undef CVT

    #pragma unroll
    for (int ks = 0; ks <= (HASH ? 4 : 0); ++ks) {
        const unsigned short* gs = Bg + (ks == 0 ? (size_t)o * 21504
                                      : (size_t)(63 + ks) * 21504);
        bf16x8 ahi, alo;
        if (ks) { // A slice from f32 h, split hi/lo in-register
            const float* ap = hin + (size_t)(c0w + j15) * 128 + (ks - 1) * 32 + qr * 8;
            float4 a0 = *(const float4*)ap;
            float4 a1 = *(const float4*)(ap + 4);
            #define CVT(e, val) { unsigned short hh = f2bf(val); \
                ahi[e] = (short)hh; alo[e] = (short)f2bf((val) - bf2f(hh)); }
            CVT(0, a0.x) CVT(1, a0.y) CVT(2, a0.z) CVT(3, a0.w)
            CVT(4, a1.x) CVT(5, a1.y) CVT(6, a1.z) CVT(7, a1.w)
            #undef CVT
        }

        if (ks == 0) {
            #pragma unroll
            for (int s = 0; s < 21; ++s) {
                const unsigned short* bb = gs + ((s * 4 + qr) * 16 + j15) * 8;
                bf16x8 bhi = *(const bf16x8*)bb;
                bf16x8 blo = *(const bf16x8*)(bb + 10752);
                acc[s] = __builtin_amdgcn_mfma_f32_16x16x32_bf16(axhi, bhi, acc[s], 0, 0, 0);
                acc[s] = __builtin_amdgcn_mfma_f32_16x16x32_bf16(axlo, bhi, acc[s], 0, 0, 0);
                acc[s] = __builtin_amdgcn_mfma_f32_16x16x32_bf16(axhi, blo, acc[s], 0, 0, 0);
            }
        } else if constexpr (HASH) {
            #pragma unroll
            for (int s = 0; s < 21; ++s) {
                const int d = (s < 14) ? s : s + 7;
                const unsigned short* bb = gs + ((s * 4 + qr) * 16 + j15) * 8;
                bf16x8 bhi = *(const bf16x8*)bb;
                bf16x8 blo = *(const bf16x8*)(bb + 10752);
                acc[d] = __builtin_amdgcn_mfma_f32_16x16x32_bf16(ahi, bhi, acc[d], 0, 0, 0);
                acc[d] = __builtin_amdgcn_mfma_f32_16x16x32_bf16(alo, bhi, acc[d], 0, 0, 0);
                acc[d] = __builtin_amdgcn_mfma_f32_16x16x32_bf16(ahi, blo, acc[d], 0, 0, 0);
            }
        }
    }

    #pragma unroll
    for (int t = 0; t < 7; ++t) {
        const int u = t * 16 + j15;
        const float bh = (u < 100) ? bhh[200 + u] : 0.f;  // h_n bias
        float hv0, hv1, hv2, hv3;
        #define GATE(reg, hvout) { \
            float rr = sigmoidf_(acc[t][reg]); \
            float zz = sigmoidf_(acc[t + 7][reg]); \
            float nn = tanhf_(acc[t + 14][reg] + rr * (acc[t + 21][reg] + bh)); \
            float hcv = 0.f; \
            if constexpr (HASH) hcv = hin[(size_t)(c0w + qr * 4 + reg) * 128 + u]; \
            hvout = nn + zz * (hcv - nn); }
        GATE(0, hv0) GATE(1, hv1) GATE(2, hv2) GATE(3, hv3)
        #undef GATE
        if (last) {
            float* r0 = hout + (size_t)(c0w + qr * 4) * 128 + u;
            r0[0]   = hv0;
            r0[128] = hv1;
            r0[256] = hv2;
            r0[384] = hv3;
        } else {
            float* r0 = hout + (size_t)((c0w >> 1) + qr * 2) * 128 + u;
            r0[0]   = hv0 + hv1;
            r0[128] = hv2 + hv3;
        }
    }
    {
        const int u2 = 112 + j15;
        if (last) {
            #pragma unroll
            for (int reg = 0; reg < 4; ++reg)
                hout[(size_t)(c0w + qr * 4 + reg) * 128 + u2] = 0.f;
        } else {
            #pragma unroll
            for (int p = 0; p < 2; ++p)
                hout[(size_t)((c0w >> 1) + qr * 2 + p) * 128 + u2] = 0.f;
        }
    }
}

// ---------------------------------------------------------------------------
// MLP head + logsumexp (unchanged — verified, off the critical path).
// ---------------------------------------------------------------------------
__global__ __launch_bounds__(256) void mlp_lse(
    const float* __restrict__ h0,   // [4096][128] f32
    const float* __restrict__ W1T,  // [100][50]
    const float* __restrict__ b1,
    const float* __restrict__ W2T,  // [50][25]
    const float* __restrict__ b2,
    const float* __restrict__ W3,
    const float* __restrict__ b3,
    float* __restrict__ out)
{
    __shared__ float hs[64 * 101];
    __shared__ float w1s[5008];
    __shared__ float w2s[1250];
    __shared__ float y1s[64 * 50];

    const int o = blockIdx.x;
    const int tid = threadIdx.x;
    const int lane = tid & 63;
    const int wid = tid >> 6;

    for (int f = tid; f < 6400; f += 256) {
        int cl = f / 100, g = f - cl * 100;
        hs[cl * 101 + g] = h0[(size_t)(o * 64 + cl) * 128 + g];
    }
    for (int f = tid; f < 5000; f += 256) w1s[f] = W1T[f];
    for (int f = tid; f < 1250; f += 256) w2s[f] = W2T[f];
    __syncthreads();

    const int jbase = wid * 13;
    const int jn = (wid < 3) ? 13 : 11;       // 13+13+13+11 = 50
    float y1[13];
    #pragma unroll
    for (int jj = 0; jj < 13; ++jj) y1[jj] = b1[jbase + jj < 50 ? jbase + jj : 49];
    #pragma unroll 2
    for (int g = 0; g < 100; ++g) {
        float rg = hs[lane * 101 + g];
        const float* wr = w1s + g * 50 + jbase;
        #pragma unroll
        for (int jj = 0; jj < 13; ++jj) y1[jj] = fmaf(rg, wr[jj], y1[jj]);
    }
    #pragma unroll
    for (int jj = 0; jj < 13; ++jj)
        if (jj < jn) y1s[lane * 50 + jbase + jj] = y1[jj];
    __syncthreads();
    if (wid != 0) return;

    const int p = lane;
    float y2[25];
    #pragma unroll
    for (int i = 0; i < 25; ++i) y2[i] = b2[i];
    #pragma unroll 2
    for (int j = 0; j < 50; ++j) {
        float v = fmaxf(y1s[p * 50 + j], 0.0f);
        const float* wr = w2s + j * 25;
        #pragma unroll
        for (int i = 0; i < 25; ++i) y2[i] = fmaf(v, wr[i], y2[i]);
    }

    float cv = b3[0];
    #pragma unroll
    for (int i = 0; i < 25; ++i) cv = fmaf(fmaxf(y2[i], 0.0f), W3[i], cv);

    float m = cv;
    #pragma unroll
    for (int s = 1; s < 64; s <<= 1) m = fmaxf(m, __shfl_xor(m, s));
    float e = __expf(cv - m);
    #pragma unroll
    for (int s = 1; s < 64; s <<= 1) e += __shfl_xor(e, s);
    if (p == 0) out[o] = m + __logf(e) - 4.1588830833596715f; // log(64)
}

// ---------------------------------------------------------------------------
extern "C" void kernel_launch(void* const* d_in, const int* in_sizes, int n_in,
                              void* d_out, int out_size, void* d_ws, size_t ws_size,
                              hipStream_t stream)
{
    const float* obs  = (const float*)d_in[0];
    const float* samp = (const float*)d_in[1];
    const float* addr = (const float*)d_in[2];
    const float* W_ih = (const float*)d_in[3];
    const float* W_hh = (const float*)d_in[4];
    const float* b_ih = (const float*)d_in[5];
    const float* b_hh = (const float*)d_in[6];
    const float* W1   = (const float*)d_in[7];
    const float* b1   = (const float*)d_in[8];
    const float* W2   = (const float*)d_in[9];
    const float* b2   = (const float*)d_in[10];
    const float* W3   = (const float*)d_in[11];
    const float* b3   = (const float*)d_in[12];
    float* out = (float*)d_out;

    float* ws = (float*)d_ws;
    // Bg: 68 slabs * 21504 ush = 1462272 ush = 731136 floats
    unsigned short* Bg = (unsigned short*)ws;
    float* W1T = ws + 731136;                 // 5000
    float* W2T = ws + 736136;                 // 1250
    float* hA  = ws + 737392;                 // 65536*128 = 8388608 f
    float* hB  = ws + 9126000;                // 32768*128 = 4194304 f

    // threads: 688128 (ks0 slabs) + 43008 (H slabs) + 5000 + 1250 = 737386
    precompute_kernel<<<(737386 + 63) / 64, 64, 0, stream>>>(
        obs, W_ih, W_hh, b_ih, b_hh, W1, W2, Bg, W1T, W2T);

    // leaf lw=5: 131072 cells -> pairsum 65536 rows (hA)
    gru_level<false, 4><<<2048, 256, 0, stream>>>(Bg, b_hh, samp, addr,
        nullptr, hA, 5, 0);
    // L4: 65536 cells (hA) -> 32768 (hB)
    gru_level<true, 4><<<1024, 256, 0, stream>>>(Bg, b_hh, samp, addr, hA, hB, 4, 0);
    // L3: 32768 (hB) -> 16384 (hA)
    gru_level<true, 4><<<512, 256, 0, stream>>>(Bg, b_hh, samp, addr, hB, hA, 3, 0);
    // L2: 16384 (hA) -> 8192 (hB)
    gru_level<true, 4><<<256, 256, 0, stream>>>(Bg, b_hh, samp, addr, hA, hB, 2, 0);
    // L1: 8192 (hB) -> 4096 (hA) — barrier-free, so 1-wave blocks spread wide
    gru_level<true, 1><<<512, 64, 0, stream>>>(Bg, b_hh, samp, addr, hB, hA, 1, 0);
    // L0 (root, last): 4096 (hA) -> 4096 (hB)
    gru_level<true, 1><<<256, 64, 0, stream>>>(Bg, b_hh, samp, addr, hA, hB, 0, 1);

    mlp_lse<<<64, 256, 0, stream>>>(hB, W1T, b1, W2T, b2, W3, b3, out);
}

// Round 15
// 197.685 us; speedup vs baseline: 1.3386x; 1.3386x over previous
//
#include <hip/hip_runtime.h>
#include <hip/hip_bf16.h>

typedef __attribute__((ext_vector_type(8))) short bf16x8;
typedef __attribute__((ext_vector_type(4))) float f32x4;

__device__ __forceinline__ float sigmoidf_(float x){ return 1.0f/(1.0f+__expf(-x)); }
__device__ __forceinline__ float tanhf_(float x){ return 1.0f - 2.0f/(1.0f+__expf(2.0f*x)); }
__device__ __forceinline__ unsigned short f2bf(float f){
    __hip_bfloat16 b = __float2bfloat16(f);
    return *reinterpret_cast<unsigned short*>(&b);
}
__device__ __forceinline__ float bf2f(unsigned short u){
    __hip_bfloat16 b = *reinterpret_cast<__hip_bfloat16*>(&u);
    return __bfloat162float(b);
}

// ---------------------------------------------------------------------------
// Layouts (unchanged — verified correct):
//  Bg (ushort): 68 slabs of 21504 ush; slab = [plane hi/lo][21 slots][4 qr][16 j][8 e];
//   plane stride 10752 ush (= 21504 B = 1344 float4; full slab = 2688 float4).
//   Slabs 0..63  = per-o ks0: kk<18 -> W_ih[gate][100+kk]; kk==18 -> bias row
//     (b_ih(+b_hh for r/z) + obs.W_ih[:, :100]); A supplies 1.0 at k=18.
//   Slabs 64..67 = H ksteps 1..4 of W_hh. Slots 0..13 -> tiles 0..13 (r,z);
//     slots 14..20 -> tiles 21..27 (hn). REGION 3 (hn) uses gate rows 200+u!
//  h (float32): [rows][128]; cols 112..127 zeroed explicitly.
// ---------------------------------------------------------------------------
__global__ __launch_bounds__(64) void precompute_kernel(
    const float* __restrict__ obs, const float* __restrict__ W_ih,
    const float* __restrict__ W_hh, const float* __restrict__ b_ih,
    const float* __restrict__ b_hh, const float* __restrict__ W1,
    const float* __restrict__ W2,
    unsigned short* __restrict__ Bg,
    float* __restrict__ W1T, float* __restrict__ W2T)
{
    int t = blockIdx.x * 64 + threadIdx.x;
    if (t < 688128) { // ks0 slabs, one per o: 64 * 10752 positions (per plane)
        int o = t / 10752, r = t % 10752;
        int s = r / 512, r2 = r % 512;
        int j = r2 / 32, kk = r2 % 32;
        int region = s / 7;                 // 0=r,1=z,2=i_n
        int u = (s % 7) * 16 + j;
        float wv = 0.f;
        if (u < 100) {
            int gate = region * 100 + u;
            if (kk < 18) {
                wv = W_ih[(size_t)gate * 118 + 100 + kk];
            } else if (kk == 18) { // bias row
                wv = b_ih[gate] + (region < 2 ? b_hh[gate] : 0.f);
                const float* orow = obs + o * 100;
                const float* wrow = W_ih + (size_t)gate * 118;
                for (int k = 0; k < 100; ++k) wv = fmaf(orow[k], wrow[k], wv);
            }
        }
        unsigned short h = f2bf(wv);
        unsigned short l = f2bf(wv - bf2f(h));
        int qr = kk >> 3, e = kk & 7;
        size_t base = (size_t)o * 21504 + (size_t)((s * 4 + qr) * 16 + j) * 8 + e;
        Bg[base] = h;
        Bg[base + 10752] = l;
        return;
    }
    t -= 688128;
    if (t < 43008) { // H slabs (ks 1..4): 4 * 10752 positions
        int ks = 1 + t / 10752, r = t % 10752;
        int s = r / 512, r2 = r % 512;
        int j = r2 / 32, kk = r2 % 32;
        int tt = (s < 14) ? s : s + 7;
        int region = tt / 7;
        int u = (tt % 7) * 16 + j;
        float wv = 0.f;
        if (u < 100) {
            // region 3 (h_n) uses the SAME n-gate rows (200+u) as region 2
            int gate = (region == 3 ? 2 : region) * 100 + u;
            int kh = (ks - 1) * 32 + kk;
            if (kh < 100) wv = W_hh[(size_t)gate * 100 + kh];
        }
        unsigned short h = f2bf(wv);
        unsigned short l = f2bf(wv - bf2f(h));
        int qr = kk >> 3, e = kk & 7;
        size_t base = (size_t)(64 + ks - 1) * 21504
                    + (size_t)((s * 4 + qr) * 16 + j) * 8 + e;
        Bg[base] = h;
        Bg[base + 10752] = l;
        return;
    }
    t -= 43008;
    if (t < 5000) { int g = t / 50, j = t % 50; W1T[t] = W1[j * 100 + g]; return; }
    t -= 5000;
    if (t < 1250) { int j = t / 25, i = t % 25; W2T[t] = W2[i * 50 + j]; }
}

// ---------------------------------------------------------------------------
// GRU level via MFMA — R11 structure (best measured: two-plane 43 KB LDS
// staging, 2 barriers per kstep, NW=8 big levels) + XCD swizzle only.
// acc[28] f32x4 zero-init: tiles 0-6=r, 7-13=z, 14-20=i_n, 21-27=h_n.
// Split-bf16: D += Ahi*Bhi + Alo*Bhi + Ahi*Blo (order per acc unchanged).
// ---------------------------------------------------------------------------
template<bool HASH, int NW>
__global__ __launch_bounds__(NW * 64) void gru_level(
    const unsigned short* __restrict__ Bg,  // 68 slabs (see layout)
    const float* __restrict__ bhh,          // b_hh (for h_n bias rows 200+u)
    const float* __restrict__ samp,         // (O,P,63,8)
    const float* __restrict__ addr,         // (O,P,63,10)
    const float* __restrict__ hin,          // [cellsIn][128] f32
    float* __restrict__ hout,               // [rowsOut][128] f32
    int lw, int last)
{
    __shared__ unsigned short Blds[21504];  // 43008 B = 2688 float4 (hi+lo!)

    const int tid = threadIdx.x;
    const int lane = tid & 63;
    const int wid = tid >> 6;
    const int j15 = lane & 15;
    const int qr = lane >> 4;
    // XCD swizzle: consecutive work indices land on the same XCD (grid % 8 == 0)
    const int wk = (blockIdx.x & 7) * (gridDim.x >> 3) + (blockIdx.x >> 3);
    const int c0 = wk * (NW * 16);
    const int c0w = c0 + wid * 16;
    const int o = c0w >> (lw + 6);          // uniform per block at these configs

    f32x4 acc[28];
    #pragma unroll
    for (int t = 0; t < 28; ++t) acc[t] = (f32x4){0.f, 0.f, 0.f, 0.f};

    const int w = 1 << lw;
    const int cm = c0w + j15;
    const int opm = cm >> lw;
    const int nodem = w - 1 + (cm & (w - 1));
    const size_t nb = (size_t)opm * 63 + nodem;
    float xv0=0.f,xv1=0.f,xv2=0.f,xv3=0.f,xv4=0.f,xv5=0.f,xv6=0.f,xv7=0.f;
    if (qr == 0) {
        const float4* s4 = (const float4*)(samp + nb * 8);
        float4 a = s4[0], b = s4[1];
        xv0=a.x; xv1=a.y; xv2=a.z; xv3=a.w; xv4=b.x; xv5=b.y; xv6=b.z; xv7=b.w;
    } else if (qr == 1) {
        const float2* a2 = (const float2*)(addr + nb * 10);
        float2 e0=a2[0], e1=a2[1], e2=a2[2], e3=a2[3];
        xv0=e0.x; xv1=e0.y; xv2=e1.x; xv3=e1.y; xv4=e2.x; xv5=e2.y; xv6=e3.x; xv7=e3.y;
    } else if (qr == 2) {
        xv0 = addr[nb * 10 + 8]; xv1 = addr[nb * 10 + 9];
        xv2 = 1.0f;                          // bias row k=18
    }
    bf16x8 axhi, axlo;
    #define CVT(e, val) { unsigned short hh = f2bf(val); \
        axhi[e] = (short)hh; axlo[e] = (short)f2bf((val) - bf2f(hh)); }
    CVT(0, xv0) CVT(1, xv1) CVT(2, xv2) CVT(3, xv3)
    CVT(4, xv4) CVT(5, xv5) CVT(6, xv6) CVT(7, xv7)
    #undef CVT

    #pragma unroll
    for (int ks = 0; ks <= (HASH ? 4 : 0); ++ks) {
        if (ks) __syncthreads();            // protect slab overwrite
        {
            const unsigned short* gs = Bg + (ks == 0 ? (size_t)o * 21504
                                          : (size_t)(63 + ks) * 21504);
            const float4* src = (const float4*)gs;
            float4* dst = (float4*)Blds;
            // slab = 21504 ush * 2 B / 16 B = 2688 float4 (hi AND lo planes)
            #pragma unroll
            for (int i = tid; i < 2688; i += NW * 64) dst[i] = src[i];
        }
        bf16x8 ahi, alo;
        if (ks) { // A slice from f32 h, split hi/lo in-register
            const float* ap = hin + (size_t)(c0w + j15) * 128 + (ks - 1) * 32 + qr * 8;
            float4 a0 = *(const float4*)ap;
            float4 a1 = *(const float4*)(ap + 4);
            #define CVT(e, val) { unsigned short hh = f2bf(val); \
                ahi[e] = (short)hh; alo[e] = (short)f2bf((val) - bf2f(hh)); }
            CVT(0, a0.x) CVT(1, a0.y) CVT(2, a0.z) CVT(3, a0.w)
            CVT(4, a1.x) CVT(5, a1.y) CVT(6, a1.z) CVT(7, a1.w)
            #undef CVT
        }
        __syncthreads();                    // slab staged

        if (ks == 0) {
            #pragma unroll
            for (int s = 0; s < 21; ++s) {
                const unsigned short* bb = Blds + ((s * 4 + qr) * 16 + j15) * 8;
                bf16x8 bhi = *(const bf16x8*)bb;
                bf16x8 blo = *(const bf16x8*)(bb + 10752);
                acc[s] = __builtin_amdgcn_mfma_f32_16x16x32_bf16(axhi, bhi, acc[s], 0, 0, 0);
                acc[s] = __builtin_amdgcn_mfma_f32_16x16x32_bf16(axlo, bhi, acc[s], 0, 0, 0);
                acc[s] = __builtin_amdgcn_mfma_f32_16x16x32_bf16(axhi, blo, acc[s], 0, 0, 0);
            }
        } else if constexpr (HASH) {
            #pragma unroll
            for (int s = 0; s < 21; ++s) {
                const int d = (s < 14) ? s : s + 7;
                const unsigned short* bb = Blds + ((s * 4 + qr) * 16 + j15) * 8;
                bf16x8 bhi = *(const bf16x8*)bb;
                bf16x8 blo = *(const bf16x8*)(bb + 10752);
                acc[d] = __builtin_amdgcn_mfma_f32_16x16x32_bf16(ahi, bhi, acc[d], 0, 0, 0);
                acc[d] = __builtin_amdgcn_mfma_f32_16x16x32_bf16(alo, bhi, acc[d], 0, 0, 0);
                acc[d] = __builtin_amdgcn_mfma_f32_16x16x32_bf16(ahi, blo, acc[d], 0, 0, 0);
            }
        }
    }

    #pragma unroll
    for (int t = 0; t < 7; ++t) {
        const int u = t * 16 + j15;
        const float bh = (u < 100) ? bhh[200 + u] : 0.f;  // h_n bias
        float hv0, hv1, hv2, hv3;
        #define GATE(reg, hvout) { \
            float rr = sigmoidf_(acc[t][reg]); \
            float zz = sigmoidf_(acc[t + 7][reg]); \
            float nn = tanhf_(acc[t + 14][reg] + rr * (acc[t + 21][reg] + bh)); \
            float hcv = 0.f; \
            if constexpr (HASH) hcv = hin[(size_t)(c0w + qr * 4 + reg) * 128 + u]; \
            hvout = nn + zz * (hcv - nn); }
        GATE(0, hv0) GATE(1, hv1) GATE(2, hv2) GATE(3, hv3)
        #undef GATE
        if (last) {
            float* r0 = hout + (size_t)(c0w + qr * 4) * 128 + u;
            r0[0]   = hv0;
            r0[128] = hv1;
            r0[256] = hv2;
            r0[384] = hv3;
        } else {
            float* r0 = hout + (size_t)((c0w >> 1) + qr * 2) * 128 + u;
            r0[0]   = hv0 + hv1;
            r0[128] = hv2 + hv3;
        }
    }
    {
        const int u2 = 112 + j15;
        if (last) {
            #pragma unroll
            for (int reg = 0; reg < 4; ++reg)
                hout[(size_t)(c0w + qr * 4 + reg) * 128 + u2] = 0.f;
        } else {
            #pragma unroll
            for (int p = 0; p < 2; ++p)
                hout[(size_t)((c0w >> 1) + qr * 2 + p) * 128 + u2] = 0.f;
        }
    }
}

// ---------------------------------------------------------------------------
// MLP head + logsumexp (unchanged — verified, off the critical path).
// ---------------------------------------------------------------------------
__global__ __launch_bounds__(256) void mlp_lse(
    const float* __restrict__ h0,   // [4096][128] f32
    const float* __restrict__ W1T,  // [100][50]
    const float* __restrict__ b1,
    const float* __restrict__ W2T,  // [50][25]
    const float* __restrict__ b2,
    const float* __restrict__ W3,
    const float* __restrict__ b3,
    float* __restrict__ out)
{
    __shared__ float hs[64 * 101];
    __shared__ float w1s[5008];
    __shared__ float w2s[1250];
    __shared__ float y1s[64 * 50];

    const int o = blockIdx.x;
    const int tid = threadIdx.x;
    const int lane = tid & 63;
    const int wid = tid >> 6;

    for (int f = tid; f < 6400; f += 256) {
        int cl = f / 100, g = f - cl * 100;
        hs[cl * 101 + g] = h0[(size_t)(o * 64 + cl) * 128 + g];
    }
    for (int f = tid; f < 5000; f += 256) w1s[f] = W1T[f];
    for (int f = tid; f < 1250; f += 256) w2s[f] = W2T[f];
    __syncthreads();

    const int jbase = wid * 13;
    const int jn = (wid < 3) ? 13 : 11;       // 13+13+13+11 = 50
    float y1[13];
    #pragma unroll
    for (int jj = 0; jj < 13; ++jj) y1[jj] = b1[jbase + jj < 50 ? jbase + jj : 49];
    #pragma unroll 2
    for (int g = 0; g < 100; ++g) {
        float rg = hs[lane * 101 + g];
        const float* wr = w1s + g * 50 + jbase;
        #pragma unroll
        for (int jj = 0; jj < 13; ++jj) y1[jj] = fmaf(rg, wr[jj], y1[jj]);
    }
    #pragma unroll
    for (int jj = 0; jj < 13; ++jj)
        if (jj < jn) y1s[lane * 50 + jbase + jj] = y1[jj];
    __syncthreads();
    if (wid != 0) return;

    const int p = lane;
    float y2[25];
    #pragma unroll
    for (int i = 0; i < 25; ++i) y2[i] = b2[i];
    #pragma unroll 2
    for (int j = 0; j < 50; ++j) {
        float v = fmaxf(y1s[p * 50 + j], 0.0f);
        const float* wr = w2s + j * 25;
        #pragma unroll
        for (int i = 0; i < 25; ++i) y2[i] = fmaf(v, wr[i], y2[i]);
    }

    float cv = b3[0];
    #pragma unroll
    for (int i = 0; i < 25; ++i) cv = fmaf(fmaxf(y2[i], 0.0f), W3[i], cv);

    float m = cv;
    #pragma unroll
    for (int s = 1; s < 64; s <<= 1) m = fmaxf(m, __shfl_xor(m, s));
    float e = __expf(cv - m);
    #pragma unroll
    for (int s = 1; s < 64; s <<= 1) e += __shfl_xor(e, s);
    if (p == 0) out[o] = m + __logf(e) - 4.1588830833596715f; // log(64)
}

// ---------------------------------------------------------------------------
extern "C" void kernel_launch(void* const* d_in, const int* in_sizes, int n_in,
                              void* d_out, int out_size, void* d_ws, size_t ws_size,
                              hipStream_t stream)
{
    const float* obs  = (const float*)d_in[0];
    const float* samp = (const float*)d_in[1];
    const float* addr = (const float*)d_in[2];
    const float* W_ih = (const float*)d_in[3];
    const float* W_hh = (const float*)d_in[4];
    const float* b_ih = (const float*)d_in[5];
    const float* b_hh = (const float*)d_in[6];
    const float* W1   = (const float*)d_in[7];
    const float* b1   = (const float*)d_in[8];
    const float* W2   = (const float*)d_in[9];
    const float* b2   = (const float*)d_in[10];
    const float* W3   = (const float*)d_in[11];
    const float* b3   = (const float*)d_in[12];
    float* out = (float*)d_out;

    float* ws = (float*)d_ws;
    // Bg: 68 slabs * 21504 ush = 1462272 ush = 731136 floats
    unsigned short* Bg = (unsigned short*)ws;
    float* W1T = ws + 731136;                 // 5000
    float* W2T = ws + 736136;                 // 1250
    float* hA  = ws + 737392;                 // 65536*128 = 8388608 f
    float* hB  = ws + 9126000;                // 32768*128 = 4194304 f

    // threads: 688128 (ks0 slabs) + 43008 (H slabs) + 5000 + 1250 = 737386
    precompute_kernel<<<(737386 + 63) / 64, 64, 0, stream>>>(
        obs, W_ih, W_hh, b_ih, b_hh, W1, W2, Bg, W1T, W2T);

    // R11 launch config (best measured) — all grids % 8 == 0 for the swizzle
    // leaf lw=5: 131072 cells -> pairsum 65536 rows (hA)
    gru_level<false, 8><<<1024, 512, 0, stream>>>(Bg, b_hh, samp, addr,
        nullptr, hA, 5, 0);
    // L4: 65536 cells (hA) -> 32768 (hB)
    gru_level<true, 8><<<512, 512, 0, stream>>>(Bg, b_hh, samp, addr, hA, hB, 4, 0);
    // L3: 32768 (hB) -> 16384 (hA)
    gru_level<true, 8><<<256, 512, 0, stream>>>(Bg, b_hh, samp, addr, hB, hA, 3, 0);
    // L2: 16384 (hA) -> 8192 (hB)
    gru_level<true, 4><<<256, 256, 0, stream>>>(Bg, b_hh, samp, addr, hA, hB, 2, 0);
    // L1: 8192 (hB) -> 4096 (hA)
    gru_level<true, 4><<<128, 256, 0, stream>>>(Bg, b_hh, samp, addr, hB, hA, 1, 0);
    // L0 (root, last): 4096 (hA) -> 4096 (hB)
    gru_level<true, 4><<<64, 256, 0, stream>>>(Bg, b_hh, samp, addr, hA, hB, 0, 1);

    mlp_lse<<<64, 256, 0, stream>>>(hB, W1T, b1, W2T, b2, W3, b3, out);
}

// Round 16
// 179.253 us; speedup vs baseline: 1.4763x; 1.1028x over previous
//
#include <hip/hip_runtime.h>
#include <hip/hip_bf16.h>

typedef __attribute__((ext_vector_type(8))) short bf16x8;
typedef __attribute__((ext_vector_type(4))) float f32x4;

__device__ __forceinline__ float sigmoidf_(float x){ return 1.0f/(1.0f+__expf(-x)); }
__device__ __forceinline__ float tanhf_(float x){ return 1.0f - 2.0f/(1.0f+__expf(2.0f*x)); }
__device__ __forceinline__ unsigned short f2bf(float f){
    __hip_bfloat16 b = __float2bfloat16(f);
    return *reinterpret_cast<unsigned short*>(&b);
}
__device__ __forceinline__ float bf2f(unsigned short u){
    __hip_bfloat16 b = *reinterpret_cast<__hip_bfloat16*>(&u);
    return __bfloat162float(b);
}

// ---------------------------------------------------------------------------
// Layouts (Bg / W1T / W2T unchanged — verified through R15):
//  Bg (ushort): 68 slabs of 21504 ush; slab = [plane hi/lo][21 slots][4 qr][16 j][8 e];
//   plane stride 10752 ush (= 21504 B = 1344 float4; full slab = 2688 float4).
//   Slabs 0..63  = per-o ks0: kk<18 -> W_ih[gate][100+kk]; kk==18 -> bias row
//     (b_ih(+b_hh for r/z) + obs.W_ih[:, :100]); A supplies 1.0 at k=18.
//   Slabs 64..67 = H ksteps 1..4 of W_hh. Slots 0..13 -> tiles 0..13 (r,z);
//     slots 14..20 -> tiles 21..27 (hn). REGION 3 (hn) uses gate rows 200+u!
//  h (float32, global): [rows][128]; cols 100..127 are 0.
//  h-mid (bf16, LDS): [64 rows][136 ush]; cols 0..99 data, 100..127 zero.
// ---------------------------------------------------------------------------
__global__ __launch_bounds__(64) void precompute_kernel(
    const float* __restrict__ obs, const float* __restrict__ W_ih,
    const float* __restrict__ W_hh, const float* __restrict__ b_ih,
    const float* __restrict__ b_hh, const float* __restrict__ W1,
    const float* __restrict__ W2,
    unsigned short* __restrict__ Bg,
    float* __restrict__ W1T, float* __restrict__ W2T)
{
    int t = blockIdx.x * 64 + threadIdx.x;
    if (t < 688128) { // ks0 slabs, one per o: 64 * 10752 positions (per plane)
        int o = t / 10752, r = t % 10752;
        int s = r / 512, r2 = r % 512;
        int j = r2 / 32, kk = r2 % 32;
        int region = s / 7;                 // 0=r,1=z,2=i_n
        int u = (s % 7) * 16 + j;
        float wv = 0.f;
        if (u < 100) {
            int gate = region * 100 + u;
            if (kk < 18) {
                wv = W_ih[(size_t)gate * 118 + 100 + kk];
            } else if (kk == 18) { // bias row
                wv = b_ih[gate] + (region < 2 ? b_hh[gate] : 0.f);
                const float* orow = obs + o * 100;
                const float* wrow = W_ih + (size_t)gate * 118;
                for (int k = 0; k < 100; ++k) wv = fmaf(orow[k], wrow[k], wv);
            }
        }
        unsigned short h = f2bf(wv);
        unsigned short l = f2bf(wv - bf2f(h));
        int qr = kk >> 3, e = kk & 7;
        size_t base = (size_t)o * 21504 + (size_t)((s * 4 + qr) * 16 + j) * 8 + e;
        Bg[base] = h;
        Bg[base + 10752] = l;
        return;
    }
    t -= 688128;
    if (t < 43008) { // H slabs (ks 1..4): 4 * 10752 positions
        int ks = 1 + t / 10752, r = t % 10752;
        int s = r / 512, r2 = r % 512;
        int j = r2 / 32, kk = r2 % 32;
        int tt = (s < 14) ? s : s + 7;
        int region = tt / 7;
        int u = (tt % 7) * 16 + j;
        float wv = 0.f;
        if (u < 100) {
            // region 3 (h_n) uses the SAME n-gate rows (200+u) as region 2
            int gate = (region == 3 ? 2 : region) * 100 + u;
            int kh = (ks - 1) * 32 + kk;
            if (kh < 100) wv = W_hh[(size_t)gate * 100 + kh];
        }
        unsigned short h = f2bf(wv);
        unsigned short l = f2bf(wv - bf2f(h));
        int qr = kk >> 3, e = kk & 7;
        size_t base = (size_t)(64 + ks - 1) * 21504
                    + (size_t)((s * 4 + qr) * 16 + j) * 8 + e;
        Bg[base] = h;
        Bg[base + 10752] = l;
        return;
    }
    t -= 43008;
    if (t < 5000) { int g = t / 50, j = t % 50; W1T[t] = W1[j * 100 + g]; return; }
    t -= 5000;
    if (t < 1250) { int j = t / 25, i = t % 25; W2T[t] = W2[i * 50 + j]; }
}

// ---------------------------------------------------------------------------
// FUSED level pair (LW1, LW1-1). Block = 512 thr (8 waves) = 128 level-LW1
// cells -> 64 pairsummed mid rows (bf16, LDS) -> 64 level-(LW1-1) cells
// (waves 0..3) -> global out. Intermediate h never touches HBM.
// Phase 1: R15-verified structure (full hi/lo split, 3 MFMAs/slot).
// Phase 2: A(h) = bf16 from LDS (2 MFMAs/slot on H ksteps: ahi*bhi, ahi*blo);
//          x kstep keeps the full split (3 MFMAs/slot).
// ---------------------------------------------------------------------------
template<int LW1, bool LEAF1, bool LAST>
__global__ __launch_bounds__(512) void fused_pair(
    const unsigned short* __restrict__ Bg,  // 68 slabs (see layout)
    const float* __restrict__ bhh,          // b_hh (for h_n bias rows 200+u)
    const float* __restrict__ samp,         // (O,P,63,8)
    const float* __restrict__ addr,         // (O,P,63,10)
    const float* __restrict__ hin,          // [cellsIn][128] f32 (unused if LEAF1)
    float* __restrict__ hout)               // [rowsOut][128] f32
{
    __shared__ unsigned short Blds[21504];  // 43008 B = 2688 float4 (hi+lo!)
    __shared__ unsigned short hmid[64 * 136]; // 17408 B bf16 mid-h, stride 136

    const int tid = threadIdx.x;
    const int lane = tid & 63;
    const int wid = tid >> 6;
    const int j15 = lane & 15;
    const int qr = lane >> 4;
    // XCD swizzle (grid % 8 == 0)
    const int wk = (blockIdx.x & 7) * (gridDim.x >> 3) + (blockIdx.x >> 3);
    const int c0 = wk * 128;                 // first phase-1 cell
    const int c0w = c0 + wid * 16;
    const int o = c0 >> (LW1 + 6);           // uniform per block (128 <= 64*2^LW1)

    f32x4 acc[28];
    #pragma unroll
    for (int t = 0; t < 28; ++t) acc[t] = (f32x4){0.f, 0.f, 0.f, 0.f};

    // ================= PHASE 1: level LW1, 128 cells, 8 waves =================
    {
        const int w = 1 << LW1;
        const int cm = c0w + j15;
        const int opm = cm >> LW1;
        const int nodem = w - 1 + (cm & (w - 1));
        const size_t nb = (size_t)opm * 63 + nodem;
        float xv0=0.f,xv1=0.f,xv2=0.f,xv3=0.f,xv4=0.f,xv5=0.f,xv6=0.f,xv7=0.f;
        if (qr == 0) {
            const float4* s4 = (const float4*)(samp + nb * 8);
            float4 a = s4[0], b = s4[1];
            xv0=a.x; xv1=a.y; xv2=a.z; xv3=a.w; xv4=b.x; xv5=b.y; xv6=b.z; xv7=b.w;
        } else if (qr == 1) {
            const float2* a2 = (const float2*)(addr + nb * 10);
            float2 e0=a2[0], e1=a2[1], e2=a2[2], e3=a2[3];
            xv0=e0.x; xv1=e0.y; xv2=e1.x; xv3=e1.y; xv4=e2.x; xv5=e2.y; xv6=e3.x; xv7=e3.y;
        } else if (qr == 2) {
            xv0 = addr[nb * 10 + 8]; xv1 = addr[nb * 10 + 9];
            xv2 = 1.0f;                          // bias row k=18
        }
        bf16x8 axhi, axlo;
        #define CVT(e, val) { unsigned short hh = f2bf(val); \
            axhi[e] = (short)hh; axlo[e] = (short)f2bf((val) - bf2f(hh)); }
        CVT(0, xv0) CVT(1, xv1) CVT(2, xv2) CVT(3, xv3)
        CVT(4, xv4) CVT(5, xv5) CVT(6, xv6) CVT(7, xv7)
        #undef CVT

        #pragma unroll
        for (int ks = 0; ks <= (LEAF1 ? 0 : 4); ++ks) {
            if (ks) __syncthreads();
            {
                const unsigned short* gs = Bg + (ks == 0 ? (size_t)o * 21504
                                              : (size_t)(63 + ks) * 21504);
                const float4* src = (const float4*)gs;
                float4* dst = (float4*)Blds;
                // slab = 21504 ush * 2B / 16B = 2688 float4 (hi AND lo planes)
                #pragma unroll
                for (int i = tid; i < 2688; i += 512) dst[i] = src[i];
            }
            bf16x8 ahi, alo;
            if (ks) {
                const float* ap = hin + (size_t)(c0w + j15) * 128 + (ks - 1) * 32 + qr * 8;
                float4 a0 = *(const float4*)ap;
                float4 a1 = *(const float4*)(ap + 4);
                #define CVT(e, val) { unsigned short hh = f2bf(val); \
                    ahi[e] = (short)hh; alo[e] = (short)f2bf((val) - bf2f(hh)); }
                CVT(0, a0.x) CVT(1, a0.y) CVT(2, a0.z) CVT(3, a0.w)
                CVT(4, a1.x) CVT(5, a1.y) CVT(6, a1.z) CVT(7, a1.w)
                #undef CVT
            }
            __syncthreads();

            if (ks == 0) {
                #pragma unroll
                for (int s = 0; s < 21; ++s) {
                    const unsigned short* bb = Blds + ((s * 4 + qr) * 16 + j15) * 8;
                    bf16x8 bhi = *(const bf16x8*)bb;
                    bf16x8 blo = *(const bf16x8*)(bb + 10752);
                    acc[s] = __builtin_amdgcn_mfma_f32_16x16x32_bf16(axhi, bhi, acc[s], 0, 0, 0);
                    acc[s] = __builtin_amdgcn_mfma_f32_16x16x32_bf16(axlo, bhi, acc[s], 0, 0, 0);
                    acc[s] = __builtin_amdgcn_mfma_f32_16x16x32_bf16(axhi, blo, acc[s], 0, 0, 0);
                }
            } else if constexpr (!LEAF1) {
                #pragma unroll
                for (int s = 0; s < 21; ++s) {
                    const int d = (s < 14) ? s : s + 7;
                    const unsigned short* bb = Blds + ((s * 4 + qr) * 16 + j15) * 8;
                    bf16x8 bhi = *(const bf16x8*)bb;
                    bf16x8 blo = *(const bf16x8*)(bb + 10752);
                    acc[d] = __builtin_amdgcn_mfma_f32_16x16x32_bf16(ahi, bhi, acc[d], 0, 0, 0);
                    acc[d] = __builtin_amdgcn_mfma_f32_16x16x32_bf16(alo, bhi, acc[d], 0, 0, 0);
                    acc[d] = __builtin_amdgcn_mfma_f32_16x16x32_bf16(ahi, blo, acc[d], 0, 0, 0);
                }
            }
        }

        // ---- phase-1 epilogue: gates + pairsum -> bf16 mid rows in LDS ----
        #pragma unroll
        for (int t = 0; t < 7; ++t) {
            const int u = t * 16 + j15;
            const float bh = (u < 100) ? bhh[200 + u] : 0.f;
            float hv0, hv1, hv2, hv3;
            #define GATE(reg, hvout) { \
                float rr = sigmoidf_(acc[t][reg]); \
                float zz = sigmoidf_(acc[t + 7][reg]); \
                float nn = tanhf_(acc[t + 14][reg] + rr * (acc[t + 21][reg] + bh)); \
                float hcv = 0.f; \
                if constexpr (!LEAF1) hcv = hin[(size_t)(c0w + qr * 4 + reg) * 128 + u]; \
                hvout = nn + zz * (hcv - nn); }
            GATE(0, hv0) GATE(1, hv1) GATE(2, hv2) GATE(3, hv3)
            #undef GATE
            const int r0 = wid * 8 + qr * 2;          // local mid row
            hmid[(r0)     * 136 + u] = f2bf(hv0 + hv1);
            hmid[(r0 + 1) * 136 + u] = f2bf(hv2 + hv3);
        }
        // zero mid cols 112..127 (cols 100..111 stored as computed zeros)
        for (int f = tid; f < 1024; f += 512)
            hmid[(f >> 4) * 136 + 112 + (f & 15)] = 0;
    }
    __syncthreads();   // hmid complete; phase-1 Blds reads done

    // ============ PHASE 2: level LW1-1, 64 cells, waves 0..3 compute ===========
    {
        constexpr int LW2 = LW1 - 1;
        const int c20 = c0 >> 1;                 // first phase-2 cell (global row)
        const int c2w = c20 + wid * 16;
        const bool act = (wid < 4);

        #pragma unroll
        for (int t = 0; t < 28; ++t) acc[t] = (f32x4){0.f, 0.f, 0.f, 0.f};

        bf16x8 axhi, axlo;
        if (act) {
            const int w = 1 << LW2;
            const int cm = c2w + j15;
            const int opm = cm >> LW2;
            const int nodem = w - 1 + (cm & (w - 1));
            const size_t nb = (size_t)opm * 63 + nodem;
            float xv0=0.f,xv1=0.f,xv2=0.f,xv3=0.f,xv4=0.f,xv5=0.f,xv6=0.f,xv7=0.f;
            if (qr == 0) {
                const float4* s4 = (const float4*)(samp + nb * 8);
                float4 a = s4[0], b = s4[1];
                xv0=a.x; xv1=a.y; xv2=a.z; xv3=a.w; xv4=b.x; xv5=b.y; xv6=b.z; xv7=b.w;
            } else if (qr == 1) {
                const float2* a2 = (const float2*)(addr + nb * 10);
                float2 e0=a2[0], e1=a2[1], e2=a2[2], e3=a2[3];
                xv0=e0.x; xv1=e0.y; xv2=e1.x; xv3=e1.y; xv4=e2.x; xv5=e2.y; xv6=e3.x; xv7=e3.y;
            } else if (qr == 2) {
                xv0 = addr[nb * 10 + 8]; xv1 = addr[nb * 10 + 9];
                xv2 = 1.0f;
            }
            #define CVT(e, val) { unsigned short hh = f2bf(val); \
                axhi[e] = (short)hh; axlo[e] = (short)f2bf((val) - bf2f(hh)); }
            CVT(0, xv0) CVT(1, xv1) CVT(2, xv2) CVT(3, xv3)
            CVT(4, xv4) CVT(5, xv5) CVT(6, xv6) CVT(7, xv7)
            #undef CVT
        }

        #pragma unroll
        for (int ks = 0; ks <= 4; ++ks) {
            if (ks) __syncthreads();
            {
                const unsigned short* gs = Bg + (ks == 0 ? (size_t)o * 21504
                                              : (size_t)(63 + ks) * 21504);
                const float4* src = (const float4*)gs;
                float4* dst = (float4*)Blds;
                #pragma unroll
                for (int i = tid; i < 2688; i += 512) dst[i] = src[i];
            }
            bf16x8 ahi;
            if (ks && act) { // A slice straight from bf16 mid rows (LDS)
                ahi = *(const bf16x8*)(hmid + (wid * 16 + j15) * 136
                                            + (ks - 1) * 32 + qr * 8);
            }
            __syncthreads();

            if (!act) continue;
            if (ks == 0) {
                #pragma unroll
                for (int s = 0; s < 21; ++s) {
                    const unsigned short* bb = Blds + ((s * 4 + qr) * 16 + j15) * 8;
                    bf16x8 bhi = *(const bf16x8*)bb;
                    bf16x8 blo = *(const bf16x8*)(bb + 10752);
                    acc[s] = __builtin_amdgcn_mfma_f32_16x16x32_bf16(axhi, bhi, acc[s], 0, 0, 0);
                    acc[s] = __builtin_amdgcn_mfma_f32_16x16x32_bf16(axlo, bhi, acc[s], 0, 0, 0);
                    acc[s] = __builtin_amdgcn_mfma_f32_16x16x32_bf16(axhi, blo, acc[s], 0, 0, 0);
                }
            } else {
                #pragma unroll
                for (int s = 0; s < 21; ++s) {
                    const int d = (s < 14) ? s : s + 7;
                    const unsigned short* bb = Blds + ((s * 4 + qr) * 16 + j15) * 8;
                    bf16x8 bhi = *(const bf16x8*)bb;
                    bf16x8 blo = *(const bf16x8*)(bb + 10752);
                    acc[d] = __builtin_amdgcn_mfma_f32_16x16x32_bf16(ahi, bhi, acc[d], 0, 0, 0);
                    acc[d] = __builtin_amdgcn_mfma_f32_16x16x32_bf16(ahi, blo, acc[d], 0, 0, 0);
                }
            }
        }

        if (act) {
            #pragma unroll
            for (int t = 0; t < 7; ++t) {
                const int u = t * 16 + j15;
                const float bh = (u < 100) ? bhh[200 + u] : 0.f;
                float hv0, hv1, hv2, hv3;
                #define GATE(reg, hvout) { \
                    float rr = sigmoidf_(acc[t][reg]); \
                    float zz = sigmoidf_(acc[t + 7][reg]); \
                    float nn = tanhf_(acc[t + 14][reg] + rr * (acc[t + 21][reg] + bh)); \
                    float hcv = bf2f(hmid[(wid * 16 + qr * 4 + reg) * 136 + u]); \
                    hvout = nn + zz * (hcv - nn); }
                GATE(0, hv0) GATE(1, hv1) GATE(2, hv2) GATE(3, hv3)
                #undef GATE
                if (LAST) {
                    float* r0 = hout + (size_t)(c2w + qr * 4) * 128 + u;
                    r0[0]   = hv0;
                    r0[128] = hv1;
                    r0[256] = hv2;
                    r0[384] = hv3;
                } else {
                    float* r0 = hout + (size_t)((c2w >> 1) + qr * 2) * 128 + u;
                    r0[0]   = hv0 + hv1;
                    r0[128] = hv2 + hv3;
                }
            }
            const int u2 = 112 + j15;
            if (LAST) {
                #pragma unroll
                for (int reg = 0; reg < 4; ++reg)
                    hout[(size_t)(c2w + qr * 4 + reg) * 128 + u2] = 0.f;
            } else {
                #pragma unroll
                for (int p = 0; p < 2; ++p)
                    hout[(size_t)((c2w >> 1) + qr * 2 + p) * 128 + u2] = 0.f;
            }
        }
    }
}

// ---------------------------------------------------------------------------
// MLP head + logsumexp (unchanged — verified).
// ---------------------------------------------------------------------------
__global__ __launch_bounds__(256) void mlp_lse(
    const float* __restrict__ h0,   // [4096][128] f32
    const float* __restrict__ W1T,  // [100][50]
    const float* __restrict__ b1,
    const float* __restrict__ W2T,  // [50][25]
    const float* __restrict__ b2,
    const float* __restrict__ W3,
    const float* __restrict__ b3,
    float* __restrict__ out)
{
    __shared__ float hs[64 * 101];
    __shared__ float w1s[5008];
    __shared__ float w2s[1250];
    __shared__ float y1s[64 * 50];

    const int o = blockIdx.x;
    const int tid = threadIdx.x;
    const int lane = tid & 63;
    const int wid = tid >> 6;

    for (int f = tid; f < 6400; f += 256) {
        int cl = f / 100, g = f - cl * 100;
        hs[cl * 101 + g] = h0[(size_t)(o * 64 + cl) * 128 + g];
    }
    for (int f = tid; f < 5000; f += 256) w1s[f] = W1T[f];
    for (int f = tid; f < 1250; f += 256) w2s[f] = W2T[f];
    __syncthreads();

    const int jbase = wid * 13;
    const int jn = (wid < 3) ? 13 : 11;       // 13+13+13+11 = 50
    float y1[13];
    #pragma unroll
    for (int jj = 0; jj < 13; ++jj) y1[jj] = b1[jbase + jj < 50 ? jbase + jj : 49];
    #pragma unroll 2
    for (int g = 0; g < 100; ++g) {
        float rg = hs[lane * 101 + g];
        const float* wr = w1s + g * 50 + jbase;
        #pragma unroll
        for (int jj = 0; jj < 13; ++jj) y1[jj] = fmaf(rg, wr[jj], y1[jj]);
    }
    #pragma unroll
    for (int jj = 0; jj < 13; ++jj)
        if (jj < jn) y1s[lane * 50 + jbase + jj] = y1[jj];
    __syncthreads();
    if (wid != 0) return;

    const int p = lane;
    float y2[25];
    #pragma unroll
    for (int i = 0; i < 25; ++i) y2[i] = b2[i];
    #pragma unroll 2
    for (int j = 0; j < 50; ++j) {
        float v = fmaxf(y1s[p * 50 + j], 0.0f);
        const float* wr = w2s + j * 25;
        #pragma unroll
        for (int i = 0; i < 25; ++i) y2[i] = fmaf(v, wr[i], y2[i]);
    }

    float cv = b3[0];
    #pragma unroll
    for (int i = 0; i < 25; ++i) cv = fmaf(fmaxf(y2[i], 0.0f), W3[i], cv);

    float m = cv;
    #pragma unroll
    for (int s = 1; s < 64; s <<= 1) m = fmaxf(m, __shfl_xor(m, s));
    float e = __expf(cv - m);
    #pragma unroll
    for (int s = 1; s < 64; s <<= 1) e += __shfl_xor(e, s);
    if (p == 0) out[o] = m + __logf(e) - 4.1588830833596715f; // log(64)
}

// ---------------------------------------------------------------------------
extern "C" void kernel_launch(void* const* d_in, const int* in_sizes, int n_in,
                              void* d_out, int out_size, void* d_ws, size_t ws_size,
                              hipStream_t stream)
{
    const float* obs  = (const float*)d_in[0];
    const float* samp = (const float*)d_in[1];
    const float* addr = (const float*)d_in[2];
    const float* W_ih = (const float*)d_in[3];
    const float* W_hh = (const float*)d_in[4];
    const float* b_ih = (const float*)d_in[5];
    const float* b_hh = (const float*)d_in[6];
    const float* W1   = (const float*)d_in[7];
    const float* b1   = (const float*)d_in[8];
    const float* W2   = (const float*)d_in[9];
    const float* b2   = (const float*)d_in[10];
    const float* W3   = (const float*)d_in[11];
    const float* b3   = (const float*)d_in[12];
    float* out = (float*)d_out;

    float* ws = (float*)d_ws;
    // Bg: 68 slabs * 21504 ush = 1462272 ush = 731136 floats
    unsigned short* Bg = (unsigned short*)ws;
    float* W1T = ws + 731136;                 // 5000
    float* W2T = ws + 736136;                 // 1250
    float* hA  = ws + 737392;                 // up to 65536*128 f
    float* hB  = ws + 9126000;                // up to 32768*128 f

    // threads: 688128 (ks0 slabs) + 43008 (H slabs) + 5000 + 1250 = 737386
    precompute_kernel<<<(737386 + 63) / 64, 64, 0, stream>>>(
        obs, W_ih, W_hh, b_ih, b_hh, W1, W2, Bg, W1T, W2T);

    // pair A: leaf(lw=5) + L4 — 131072 cells -> 32768 rows (hB)
    fused_pair<5, true, false><<<1024, 512, 0, stream>>>(
        Bg, b_hh, samp, addr, nullptr, hB);
    // pair B: L3 + L2 — 32768 cells (hB) -> 8192 rows (hA)
    fused_pair<3, false, false><<<256, 512, 0, stream>>>(
        Bg, b_hh, samp, addr, hB, hA);
    // pair C: L1 + L0 — 8192 cells (hA) -> 4096 rows (hB), L0 = last (no pairsum)
    fused_pair<1, false, true><<<64, 512, 0, stream>>>(
        Bg, b_hh, samp, addr, hA, hB);

    mlp_lse<<<64, 256, 0, stream>>>(hB, W1T, b1, W2T, b2, W3, b3, out);
}

// Round 17
// 162.914 us; speedup vs baseline: 1.6244x; 1.1003x over previous
//
#include <hip/hip_runtime.h>
#include <hip/hip_bf16.h>

typedef __attribute__((ext_vector_type(8))) short bf16x8;
typedef __attribute__((ext_vector_type(4))) float f32x4;

__device__ __forceinline__ float sigmoidf_(float x){ return 1.0f/(1.0f+__expf(-x)); }
__device__ __forceinline__ float tanhf_(float x){ return 1.0f - 2.0f/(1.0f+__expf(2.0f*x)); }
__device__ __forceinline__ unsigned short f2bf(float f){
    __hip_bfloat16 b = __float2bfloat16(f);
    return *reinterpret_cast<unsigned short*>(&b);
}
__device__ __forceinline__ float bf2f(unsigned short u){
    __hip_bfloat16 b = *reinterpret_cast<__hip_bfloat16*>(&u);
    return __bfloat162float(b);
}
// async global->LDS, 16B per lane; LDS dest = wave-uniform base + lane*16
__device__ __forceinline__ void gload_lds16(const void* gsrc, void* ldst){
    __builtin_amdgcn_global_load_lds(
        (const __attribute__((address_space(1))) unsigned int*)gsrc,
        (__attribute__((address_space(3))) unsigned int*)ldst,
        16, 0, 0);
}

// ---------------------------------------------------------------------------
// Layouts:
//  Bg (ushort): 68 slabs of 21504 ush; slab = [plane hi/lo][21 slots][4 qr][16 j][8 e];
//   plane stride 10752 ush (= 21504 B = 1344 float4; full slab = 2688 float4).
//   Slabs 0..63  = per-o ks0: kk<18 -> W_ih[gate][100+kk]; kk==18 -> bias row
//     (b_ih(+b_hh for r/z) + obs.W_ih[:, :100]); A supplies 1.0 at k=18.
//   Slabs 64..67 = H ksteps 1..4 of W_hh. Slots 0..13 -> tiles 0..13 (r,z);
//     slots 14..20 -> tiles 21..27 (hn). REGION 3 (hn) uses gate rows 200+u!
//  h (bf16 ushort, global): [rows][128]; cols 100..127 are 0.
//  h-mid (bf16, LDS): [64 rows][136 ush]; cols 0..99 data, 100..127 zero.
// ---------------------------------------------------------------------------
__global__ __launch_bounds__(64) void precompute_kernel(
    const float* __restrict__ obs, const float* __restrict__ W_ih,
    const float* __restrict__ W_hh, const float* __restrict__ b_ih,
    const float* __restrict__ b_hh, const float* __restrict__ W1,
    const float* __restrict__ W2,
    unsigned short* __restrict__ Bg,
    float* __restrict__ W1T, float* __restrict__ W2T)
{
    int t = blockIdx.x * 64 + threadIdx.x;
    if (t < 688128) { // ks0 slabs, one per o: 64 * 10752 positions (per plane)
        int o = t / 10752, r = t % 10752;
        int s = r / 512, r2 = r % 512;
        int j = r2 / 32, kk = r2 % 32;
        int region = s / 7;                 // 0=r,1=z,2=i_n
        int u = (s % 7) * 16 + j;
        float wv = 0.f;
        if (u < 100) {
            int gate = region * 100 + u;
            if (kk < 18) {
                wv = W_ih[(size_t)gate * 118 + 100 + kk];
            } else if (kk == 18) { // bias row
                wv = b_ih[gate] + (region < 2 ? b_hh[gate] : 0.f);
                const float* orow = obs + o * 100;
                const float* wrow = W_ih + (size_t)gate * 118;
                for (int k = 0; k < 100; ++k) wv = fmaf(orow[k], wrow[k], wv);
            }
        }
        unsigned short h = f2bf(wv);
        unsigned short l = f2bf(wv - bf2f(h));
        int qr = kk >> 3, e = kk & 7;
        size_t base = (size_t)o * 21504 + (size_t)((s * 4 + qr) * 16 + j) * 8 + e;
        Bg[base] = h;
        Bg[base + 10752] = l;
        return;
    }
    t -= 688128;
    if (t < 43008) { // H slabs (ks 1..4): 4 * 10752 positions
        int ks = 1 + t / 10752, r = t % 10752;
        int s = r / 512, r2 = r % 512;
        int j = r2 / 32, kk = r2 % 32;
        int tt = (s < 14) ? s : s + 7;
        int region = tt / 7;
        int u = (tt % 7) * 16 + j;
        float wv = 0.f;
        if (u < 100) {
            // region 3 (h_n) uses the SAME n-gate rows (200+u) as region 2
            int gate = (region == 3 ? 2 : region) * 100 + u;
            int kh = (ks - 1) * 32 + kk;
            if (kh < 100) wv = W_hh[(size_t)gate * 100 + kh];
        }
        unsigned short h = f2bf(wv);
        unsigned short l = f2bf(wv - bf2f(h));
        int qr = kk >> 3, e = kk & 7;
        size_t base = (size_t)(64 + ks - 1) * 21504
                    + (size_t)((s * 4 + qr) * 16 + j) * 8 + e;
        Bg[base] = h;
        Bg[base + 10752] = l;
        return;
    }
    t -= 43008;
    if (t < 5000) { int g = t / 50, j = t % 50; W1T[t] = W1[j * 100 + g]; return; }
    t -= 5000;
    if (t < 1250) { int j = t / 25, i = t % 25; W2T[t] = W2[i * 50 + j]; }
}

// ---------------------------------------------------------------------------
// FUSED level pair (LW1, LW1-1). Block = 512 thr (8 waves) = 128 level-LW1
// cells -> 64 pairsummed mid rows (bf16, LDS) -> 64 level-(LW1-1) cells
// (waves 0..3) -> global bf16 out. Slab staging via global_load_lds (16B).
// x kstep: full hi/lo split (3 MFMAs/slot). H ksteps: bf16 A (2 MFMAs/slot).
// ---------------------------------------------------------------------------
template<int LW1, bool LEAF1, bool LAST>
__global__ __launch_bounds__(512) void fused_pair(
    const unsigned short* __restrict__ Bg,  // 68 slabs (see layout)
    const float* __restrict__ bhh,          // b_hh (for h_n bias rows 200+u)
    const float* __restrict__ samp,         // (O,P,63,8)
    const float* __restrict__ addr,         // (O,P,63,10)
    const unsigned short* __restrict__ hin, // [cellsIn][128] bf16 (unused if LEAF1)
    unsigned short* __restrict__ hout)      // [rowsOut][128] bf16
{
    __shared__ unsigned short Blds[21504];  // 43008 B = 2688 float4 (hi+lo!)
    __shared__ unsigned short hmid[64 * 136]; // 17408 B bf16 mid-h, stride 136

    const int tid = threadIdx.x;
    const int lane = tid & 63;
    const int wid = tid >> 6;
    const int j15 = lane & 15;
    const int qr = lane >> 4;
    // XCD swizzle (grid % 8 == 0)
    const int wk = (blockIdx.x & 7) * (gridDim.x >> 3) + (blockIdx.x >> 3);
    const int c0 = wk * 128;                 // first phase-1 cell
    const int c0w = c0 + wid * 16;
    const int o = c0 >> (LW1 + 6);           // uniform per block (128 <= 64*2^LW1)

    // stage one full slab (2688 float4) via global_load_lds:
    // 5 full rounds of 512 lanes + tail 128 (waves 0,1)
    #define STAGE_SLAB(gs_) { \
        const char* gsc = (const char*)(gs_); \
        char* ldc = (char*)Blds; \
        _Pragma("unroll") \
        for (int it = 0; it < 5; ++it) { \
            const int base = it * 512 + wid * 64; \
            gload_lds16(gsc + (size_t)(base + lane) * 16, ldc + (size_t)base * 16); \
        } \
        if (wid < 2) { \
            const int base = 2560 + wid * 64; \
            gload_lds16(gsc + (size_t)(base + lane) * 16, ldc + (size_t)base * 16); \
        } }

    f32x4 acc[28];
    #pragma unroll
    for (int t = 0; t < 28; ++t) acc[t] = (f32x4){0.f, 0.f, 0.f, 0.f};

    // ================= PHASE 1: level LW1, 128 cells, 8 waves =================
    {
        const int w = 1 << LW1;
        const int cm = c0w + j15;
        const int opm = cm >> LW1;
        const int nodem = w - 1 + (cm & (w - 1));
        const size_t nb = (size_t)opm * 63 + nodem;
        float xv0=0.f,xv1=0.f,xv2=0.f,xv3=0.f,xv4=0.f,xv5=0.f,xv6=0.f,xv7=0.f;
        if (qr == 0) {
            const float4* s4 = (const float4*)(samp + nb * 8);
            float4 a = s4[0], b = s4[1];
            xv0=a.x; xv1=a.y; xv2=a.z; xv3=a.w; xv4=b.x; xv5=b.y; xv6=b.z; xv7=b.w;
        } else if (qr == 1) {
            const float2* a2 = (const float2*)(addr + nb * 10);
            float2 e0=a2[0], e1=a2[1], e2=a2[2], e3=a2[3];
            xv0=e0.x; xv1=e0.y; xv2=e1.x; xv3=e1.y; xv4=e2.x; xv5=e2.y; xv6=e3.x; xv7=e3.y;
        } else if (qr == 2) {
            xv0 = addr[nb * 10 + 8]; xv1 = addr[nb * 10 + 9];
            xv2 = 1.0f;                          // bias row k=18
        }
        bf16x8 axhi, axlo;
        #define CVT(e, val) { unsigned short hh = f2bf(val); \
            axhi[e] = (short)hh; axlo[e] = (short)f2bf((val) - bf2f(hh)); }
        CVT(0, xv0) CVT(1, xv1) CVT(2, xv2) CVT(3, xv3)
        CVT(4, xv4) CVT(5, xv5) CVT(6, xv6) CVT(7, xv7)
        #undef CVT

        #pragma unroll
        for (int ks = 0; ks <= (LEAF1 ? 0 : 4); ++ks) {
            if (ks) __syncthreads();
            const unsigned short* gs = Bg + (ks == 0 ? (size_t)o * 21504
                                          : (size_t)(63 + ks) * 21504);
            STAGE_SLAB(gs)
            bf16x8 ahi;
            if (ks) // A slice: bf16 h rows, direct load (no split)
                ahi = *(const bf16x8*)(hin + (size_t)(c0w + j15) * 128
                                           + (ks - 1) * 32 + qr * 8);
            __syncthreads();

            if (ks == 0) {
                #pragma unroll
                for (int s = 0; s < 21; ++s) {
                    const unsigned short* bb = Blds + ((s * 4 + qr) * 16 + j15) * 8;
                    bf16x8 bhi = *(const bf16x8*)bb;
                    bf16x8 blo = *(const bf16x8*)(bb + 10752);
                    acc[s] = __builtin_amdgcn_mfma_f32_16x16x32_bf16(axhi, bhi, acc[s], 0, 0, 0);
                    acc[s] = __builtin_amdgcn_mfma_f32_16x16x32_bf16(axlo, bhi, acc[s], 0, 0, 0);
                    acc[s] = __builtin_amdgcn_mfma_f32_16x16x32_bf16(axhi, blo, acc[s], 0, 0, 0);
                }
            } else if constexpr (!LEAF1) {
                #pragma unroll
                for (int s = 0; s < 21; ++s) {
                    const int d = (s < 14) ? s : s + 7;
                    const unsigned short* bb = Blds + ((s * 4 + qr) * 16 + j15) * 8;
                    bf16x8 bhi = *(const bf16x8*)bb;
                    bf16x8 blo = *(const bf16x8*)(bb + 10752);
                    acc[d] = __builtin_amdgcn_mfma_f32_16x16x32_bf16(ahi, bhi, acc[d], 0, 0, 0);
                    acc[d] = __builtin_amdgcn_mfma_f32_16x16x32_bf16(ahi, blo, acc[d], 0, 0, 0);
                }
            }
        }

        // ---- phase-1 epilogue: gates + pairsum -> bf16 mid rows in LDS ----
        #pragma unroll
        for (int t = 0; t < 7; ++t) {
            const int u = t * 16 + j15;
            const float bh = (u < 100) ? bhh[200 + u] : 0.f;
            float hv0, hv1, hv2, hv3;
            #define GATE(reg, hvout) { \
                float rr = sigmoidf_(acc[t][reg]); \
                float zz = sigmoidf_(acc[t + 7][reg]); \
                float nn = tanhf_(acc[t + 14][reg] + rr * (acc[t + 21][reg] + bh)); \
                float hcv = 0.f; \
                if constexpr (!LEAF1) \
                    hcv = bf2f(hin[(size_t)(c0w + qr * 4 + reg) * 128 + u]); \
                hvout = nn + zz * (hcv - nn); }
            GATE(0, hv0) GATE(1, hv1) GATE(2, hv2) GATE(3, hv3)
            #undef GATE
            const int r0 = wid * 8 + qr * 2;          // local mid row
            hmid[(r0)     * 136 + u] = f2bf(hv0 + hv1);
            hmid[(r0 + 1) * 136 + u] = f2bf(hv2 + hv3);
        }
        // zero mid cols 112..127 (cols 100..111 stored as computed zeros)
        for (int f = tid; f < 1024; f += 512)
            hmid[(f >> 4) * 136 + 112 + (f & 15)] = 0;
    }
    __syncthreads();   // hmid complete; phase-1 Blds reads done

    // ============ PHASE 2: level LW1-1, 64 cells, waves 0..3 compute ===========
    {
        constexpr int LW2 = LW1 - 1;
        const int c20 = c0 >> 1;                 // first phase-2 cell (global row)
        const int c2w = c20 + wid * 16;
        const bool act = (wid < 4);

        #pragma unroll
        for (int t = 0; t < 28; ++t) acc[t] = (f32x4){0.f, 0.f, 0.f, 0.f};

        bf16x8 axhi, axlo;
        if (act) {
            const int w = 1 << LW2;
            const int cm = c2w + j15;
            const int opm = cm >> LW2;
            const int nodem = w - 1 + (cm & (w - 1));
            const size_t nb = (size_t)opm * 63 + nodem;
            float xv0=0.f,xv1=0.f,xv2=0.f,xv3=0.f,xv4=0.f,xv5=0.f,xv6=0.f,xv7=0.f;
            if (qr == 0) {
                const float4* s4 = (const float4*)(samp + nb * 8);
                float4 a = s4[0], b = s4[1];
                xv0=a.x; xv1=a.y; xv2=a.z; xv3=a.w; xv4=b.x; xv5=b.y; xv6=b.z; xv7=b.w;
            } else if (qr == 1) {
                const float2* a2 = (const float2*)(addr + nb * 10);
                float2 e0=a2[0], e1=a2[1], e2=a2[2], e3=a2[3];
                xv0=e0.x; xv1=e0.y; xv2=e1.x; xv3=e1.y; xv4=e2.x; xv5=e2.y; xv6=e3.x; xv7=e3.y;
            } else if (qr == 2) {
                xv0 = addr[nb * 10 + 8]; xv1 = addr[nb * 10 + 9];
                xv2 = 1.0f;
            }
            #define CVT(e, val) { unsigned short hh = f2bf(val); \
                axhi[e] = (short)hh; axlo[e] = (short)f2bf((val) - bf2f(hh)); }
            CVT(0, xv0) CVT(1, xv1) CVT(2, xv2) CVT(3, xv3)
            CVT(4, xv4) CVT(5, xv5) CVT(6, xv6) CVT(7, xv7)
            #undef CVT
        }

        #pragma unroll
        for (int ks = 0; ks <= 4; ++ks) {
            if (ks) __syncthreads();
            const unsigned short* gs = Bg + (ks == 0 ? (size_t)o * 21504
                                          : (size_t)(63 + ks) * 21504);
            STAGE_SLAB(gs)
            bf16x8 ahi;
            if (ks && act) // A slice straight from bf16 mid rows (LDS)
                ahi = *(const bf16x8*)(hmid + (wid * 16 + j15) * 136
                                            + (ks - 1) * 32 + qr * 8);
            __syncthreads();

            if (!act) continue;
            if (ks == 0) {
                #pragma unroll
                for (int s = 0; s < 21; ++s) {
                    const unsigned short* bb = Blds + ((s * 4 + qr) * 16 + j15) * 8;
                    bf16x8 bhi = *(const bf16x8*)bb;
                    bf16x8 blo = *(const bf16x8*)(bb + 10752);
                    acc[s] = __builtin_amdgcn_mfma_f32_16x16x32_bf16(axhi, bhi, acc[s], 0, 0, 0);
                    acc[s] = __builtin_amdgcn_mfma_f32_16x16x32_bf16(axlo, bhi, acc[s], 0, 0, 0);
                    acc[s] = __builtin_amdgcn_mfma_f32_16x16x32_bf16(axhi, blo, acc[s], 0, 0, 0);
                }
            } else {
                #pragma unroll
                for (int s = 0; s < 21; ++s) {
                    const int d = (s < 14) ? s : s + 7;
                    const unsigned short* bb = Blds + ((s * 4 + qr) * 16 + j15) * 8;
                    bf16x8 bhi = *(const bf16x8*)bb;
                    bf16x8 blo = *(const bf16x8*)(bb + 10752);
                    acc[d] = __builtin_amdgcn_mfma_f32_16x16x32_bf16(ahi, bhi, acc[d], 0, 0, 0);
                    acc[d] = __builtin_amdgcn_mfma_f32_16x16x32_bf16(ahi, blo, acc[d], 0, 0, 0);
                }
            }
        }

        if (act) {
            #pragma unroll
            for (int t = 0; t < 7; ++t) {
                const int u = t * 16 + j15;
                const float bh = (u < 100) ? bhh[200 + u] : 0.f;
                float hv0, hv1, hv2, hv3;
                #define GATE(reg, hvout) { \
                    float rr = sigmoidf_(acc[t][reg]); \
                    float zz = sigmoidf_(acc[t + 7][reg]); \
                    float nn = tanhf_(acc[t + 14][reg] + rr * (acc[t + 21][reg] + bh)); \
                    float hcv = bf2f(hmid[(wid * 16 + qr * 4 + reg) * 136 + u]); \
                    hvout = nn + zz * (hcv - nn); }
                GATE(0, hv0) GATE(1, hv1) GATE(2, hv2) GATE(3, hv3)
                #undef GATE
                if (LAST) {
                    unsigned short* r0 = hout + (size_t)(c2w + qr * 4) * 128 + u;
                    r0[0]   = f2bf(hv0);
                    r0[128] = f2bf(hv1);
                    r0[256] = f2bf(hv2);
                    r0[384] = f2bf(hv3);
                } else {
                    unsigned short* r0 = hout + (size_t)((c2w >> 1) + qr * 2) * 128 + u;
                    r0[0]   = f2bf(hv0 + hv1);
                    r0[128] = f2bf(hv2 + hv3);
                }
            }
            const int u2 = 112 + j15;
            if (LAST) {
                #pragma unroll
                for (int reg = 0; reg < 4; ++reg)
                    hout[(size_t)(c2w + qr * 4 + reg) * 128 + u2] = 0;
            } else {
                #pragma unroll
                for (int p = 0; p < 2; ++p)
                    hout[(size_t)((c2w >> 1) + qr * 2 + p) * 128 + u2] = 0;
            }
        }
    }
    #undef STAGE_SLAB
}

// ---------------------------------------------------------------------------
// MLP head + logsumexp (bf16 h input; otherwise unchanged — verified).
// ---------------------------------------------------------------------------
__global__ __launch_bounds__(256) void mlp_lse(
    const unsigned short* __restrict__ h0,  // [4096][128] bf16
    const float* __restrict__ W1T,  // [100][50]
    const float* __restrict__ b1,
    const float* __restrict__ W2T,  // [50][25]
    const float* __restrict__ b2,
    const float* __restrict__ W3,
    const float* __restrict__ b3,
    float* __restrict__ out)
{
    __shared__ float hs[64 * 101];
    __shared__ float w1s[5008];
    __shared__ float w2s[1250];
    __shared__ float y1s[64 * 50];

    const int o = blockIdx.x;
    const int tid = threadIdx.x;
    const int lane = tid & 63;
    const int wid = tid >> 6;

    for (int f = tid; f < 6400; f += 256) {
        int cl = f / 100, g = f - cl * 100;
        hs[cl * 101 + g] = bf2f(h0[(size_t)(o * 64 + cl) * 128 + g]);
    }
    for (int f = tid; f < 5000; f += 256) w1s[f] = W1T[f];
    for (int f = tid; f < 1250; f += 256) w2s[f] = W2T[f];
    __syncthreads();

    const int jbase = wid * 13;
    const int jn = (wid < 3) ? 13 : 11;       // 13+13+13+11 = 50
    float y1[13];
    #pragma unroll
    for (int jj = 0; jj < 13; ++jj) y1[jj] = b1[jbase + jj < 50 ? jbase + jj : 49];
    #pragma unroll 2
    for (int g = 0; g < 100; ++g) {
        float rg = hs[lane * 101 + g];
        const float* wr = w1s + g * 50 + jbase;
        #pragma unroll
        for (int jj = 0; jj < 13; ++jj) y1[jj] = fmaf(rg, wr[jj], y1[jj]);
    }
    #pragma unroll
    for (int jj = 0; jj < 13; ++jj)
        if (jj < jn) y1s[lane * 50 + jbase + jj] = y1[jj];
    __syncthreads();
    if (wid != 0) return;

    const int p = lane;
    float y2[25];
    #pragma unroll
    for (int i = 0; i < 25; ++i) y2[i] = b2[i];
    #pragma unroll 2
    for (int j = 0; j < 50; ++j) {
        float v = fmaxf(y1s[p * 50 + j], 0.0f);
        const float* wr = w2s + j * 25;
        #pragma unroll
        for (int i = 0; i < 25; ++i) y2[i] = fmaf(v, wr[i], y2[i]);
    }

    float cv = b3[0];
    #pragma unroll
    for (int i = 0; i < 25; ++i) cv = fmaf(fmaxf(y2[i], 0.0f), W3[i], cv);

    float m = cv;
    #pragma unroll
    for (int s = 1; s < 64; s <<= 1) m = fmaxf(m, __shfl_xor(m, s));
    float e = __expf(cv - m);
    #pragma unroll
    for (int s = 1; s < 64; s <<= 1) e += __shfl_xor(e, s);
    if (p == 0) out[o] = m + __logf(e) - 4.1588830833596715f; // log(64)
}

// ---------------------------------------------------------------------------
extern "C" void kernel_launch(void* const* d_in, const int* in_sizes, int n_in,
                              void* d_out, int out_size, void* d_ws, size_t ws_size,
                              hipStream_t stream)
{
    const float* obs  = (const float*)d_in[0];
    const float* samp = (const float*)d_in[1];
    const float* addr = (const float*)d_in[2];
    const float* W_ih = (const float*)d_in[3];
    const float* W_hh = (const float*)d_in[4];
    const float* b_ih = (const float*)d_in[5];
    const float* b_hh = (const float*)d_in[6];
    const float* W1   = (const float*)d_in[7];
    const float* b1   = (const float*)d_in[8];
    const float* W2   = (const float*)d_in[9];
    const float* b2   = (const float*)d_in[10];
    const float* W3   = (const float*)d_in[11];
    const float* b3   = (const float*)d_in[12];
    float* out = (float*)d_out;

    float* ws = (float*)d_ws;
    // Bg: 68 slabs * 21504 ush = 1462272 ush = 731136 floats
    unsigned short* Bg = (unsigned short*)ws;
    float* W1T = ws + 731136;                       // 5000
    float* W2T = ws + 736136;                       // 1250
    unsigned short* hU1 = (unsigned short*)(ws + 737392);   // 32768*128 ush = 2097152 f
    unsigned short* hU2 = (unsigned short*)(ws + 2834544);  // 8192*128 ush  = 524288 f
    unsigned short* hU3 = (unsigned short*)(ws + 3358832);  // 4096*128 ush  = 262144 f

    // threads: 688128 (ks0 slabs) + 43008 (H slabs) + 5000 + 1250 = 737386
    precompute_kernel<<<(737386 + 63) / 64, 64, 0, stream>>>(
        obs, W_ih, W_hh, b_ih, b_hh, W1, W2, Bg, W1T, W2T);

    // pair A: leaf(lw=5) + L4 — 131072 cells -> 32768 rows (hU1)
    fused_pair<5, true, false><<<1024, 512, 0, stream>>>(
        Bg, b_hh, samp, addr, nullptr, hU1);
    // pair B: L3 + L2 — 32768 cells (hU1) -> 8192 rows (hU2)
    fused_pair<3, false, false><<<256, 512, 0, stream>>>(
        Bg, b_hh, samp, addr, hU1, hU2);
    // pair C: L1 + L0 — 8192 cells (hU2) -> 4096 rows (hU3), L0 = last
    fused_pair<1, false, true><<<64, 512, 0, stream>>>(
        Bg, b_hh, samp, addr, hU2, hU3);

    mlp_lse<<<64, 256, 0, stream>>>(hU3, W1T, b1, W2T, b2, W3, b3, out);
}

// Round 18
// 140.101 us; speedup vs baseline: 1.8888x; 1.1628x over previous
//
#include <hip/hip_runtime.h>
#include <hip/hip_bf16.h>

typedef __attribute__((ext_vector_type(8))) short bf16x8;
typedef __attribute__((ext_vector_type(4))) float f32x4;

__device__ __forceinline__ float sigmoidf_(float x){ return 1.0f/(1.0f+__expf(-x)); }
__device__ __forceinline__ float tanhf_(float x){ return 1.0f - 2.0f/(1.0f+__expf(2.0f*x)); }
__device__ __forceinline__ unsigned short f2bf(float f){
    __hip_bfloat16 b = __float2bfloat16(f);
    return *reinterpret_cast<unsigned short*>(&b);
}
__device__ __forceinline__ float bf2f(unsigned short u){
    __hip_bfloat16 b = *reinterpret_cast<__hip_bfloat16*>(&u);
    return __bfloat162float(b);
}
// async global->LDS, 16B per lane; LDS dest = wave-uniform base (+lane*16 implicit)
__device__ __forceinline__ void gload_lds16(const void* gsrc, void* ldst){
    __builtin_amdgcn_global_load_lds(
        (const __attribute__((address_space(1))) unsigned int*)gsrc,
        (__attribute__((address_space(3))) unsigned int*)ldst,
        16, 0, 0);
}

// ---------------------------------------------------------------------------
// Layouts:
//  Bg (ushort):
//   Slabs 0..63 (ks0, per-o): 21504 ush = [plane hi/lo][21 slots][4 qr][16 j][8 e];
//     kk<18 -> W_ih[gate][100+kk]; kk==18 -> bias row (b_ih(+b_hh for r/z) +
//     obs.W_ih[:, :100]); A supplies 1.0 at k=18. Full hi/lo split (bias precision).
//   H planes (ks 1..4, SINGLE bf16 plane each): base 1376256 + (ks-1)*10752,
//     10752 ush = [21 slots][4 qr][16 j][8 e] of W_hh rounded to bf16.
//     Slots 0..13 -> tiles 0..13 (r,z); slots 14..20 -> tiles 21..27 (hn).
//     REGION 3 (hn) uses gate rows 200+u (same n-gate rows as region 2)!
//  h (bf16 ushort, global): [rows][128]; cols 100..127 are 0.
//  Dynamic LDS (146432 B): B0 [0,21504) ush | BH [21504,64512) | hmid [64512,73216)
//   hmid = [64 rows][136 ush] bf16 mid-h.
// ---------------------------------------------------------------------------
__global__ __launch_bounds__(64) void precompute_kernel(
    const float* __restrict__ obs, const float* __restrict__ W_ih,
    const float* __restrict__ W_hh, const float* __restrict__ b_ih,
    const float* __restrict__ b_hh, const float* __restrict__ W1,
    const float* __restrict__ W2,
    unsigned short* __restrict__ Bg,
    float* __restrict__ W1T, float* __restrict__ W2T)
{
    int t = blockIdx.x * 64 + threadIdx.x;
    if (t < 688128) { // ks0 slabs, one per o: 64 * 10752 positions (per plane)
        int o = t / 10752, r = t % 10752;
        int s = r / 512, r2 = r % 512;
        int j = r2 / 32, kk = r2 % 32;
        int region = s / 7;                 // 0=r,1=z,2=i_n
        int u = (s % 7) * 16 + j;
        float wv = 0.f;
        if (u < 100) {
            int gate = region * 100 + u;
            if (kk < 18) {
                wv = W_ih[(size_t)gate * 118 + 100 + kk];
            } else if (kk == 18) { // bias row
                wv = b_ih[gate] + (region < 2 ? b_hh[gate] : 0.f);
                const float* orow = obs + o * 100;
                const float* wrow = W_ih + (size_t)gate * 118;
                for (int k = 0; k < 100; ++k) wv = fmaf(orow[k], wrow[k], wv);
            }
        }
        unsigned short h = f2bf(wv);
        unsigned short l = f2bf(wv - bf2f(h));
        int qr = kk >> 3, e = kk & 7;
        size_t base = (size_t)o * 21504 + (size_t)((s * 4 + qr) * 16 + j) * 8 + e;
        Bg[base] = h;
        Bg[base + 10752] = l;
        return;
    }
    t -= 688128;
    if (t < 43008) { // H planes (ks 1..4): 4 * 10752 positions, SINGLE bf16 plane
        int ks = 1 + t / 10752, r = t % 10752;
        int s = r / 512, r2 = r % 512;
        int j = r2 / 32, kk = r2 % 32;
        int tt = (s < 14) ? s : s + 7;
        int region = tt / 7;
        int u = (tt % 7) * 16 + j;
        float wv = 0.f;
        if (u < 100) {
            // region 3 (h_n) uses the SAME n-gate rows (200+u) as region 2
            int gate = (region == 3 ? 2 : region) * 100 + u;
            int kh = (ks - 1) * 32 + kk;
            if (kh < 100) wv = W_hh[(size_t)gate * 100 + kh];
        }
        int qr = kk >> 3, e = kk & 7;
        size_t base = (size_t)1376256 + (size_t)(ks - 1) * 10752
                    + (size_t)((s * 4 + qr) * 16 + j) * 8 + e;
        Bg[base] = f2bf(wv);
        return;
    }
    t -= 43008;
    if (t < 5000) { int g = t / 50, j = t % 50; W1T[t] = W1[j * 100 + g]; return; }
    t -= 5000;
    if (t < 1250) { int j = t / 25, i = t % 25; W2T[t] = W2[i * 50 + j]; }
}

// ---------------------------------------------------------------------------
// FUSED level pair (LW1, LW1-1) — resident-slab version. Block = 512 thr
// (8 waves). ALL weight slabs (ks0 full-split 43KB + 4 bf16 H planes 84KB)
// staged ONCE per block into 146KB dynamic LDS, then phase 1 (128 cells,
// 8 waves) and phase 2 (64 cells, waves 0..3) run all ksteps back-to-back.
// Exactly 2 block barriers. H ksteps: 1 ds_read + 1 MFMA per slot.
// ---------------------------------------------------------------------------
template<int LW1, bool LEAF1, bool LAST>
__global__ __launch_bounds__(512) void fused_pair(
    const unsigned short* __restrict__ Bg,
    const float* __restrict__ bhh,          // b_hh (for h_n bias rows 200+u)
    const float* __restrict__ samp,         // (O,P,63,8)
    const float* __restrict__ addr,         // (O,P,63,10)
    const unsigned short* __restrict__ hin, // [cellsIn][128] bf16 (unused if LEAF1)
    unsigned short* __restrict__ hout)      // [rowsOut][128] bf16
{
    extern __shared__ unsigned short smem[];
    unsigned short* B0   = smem;            // 21504 ush (hi+lo ks0 slab)
    unsigned short* BH   = smem + 21504;    // 43008 ush (4 bf16 H planes)
    unsigned short* hmid = smem + 64512;    // 8704 ush ([64][136])

    const int tid = threadIdx.x;
    const int lane = tid & 63;
    const int wid = tid >> 6;
    const int j15 = lane & 15;
    const int qr = lane >> 4;
    // XCD swizzle (grid % 8 == 0)
    const int wk = (blockIdx.x & 7) * (gridDim.x >> 3) + (blockIdx.x >> 3);
    const int c0 = wk * 128;                 // first phase-1 cell
    const int c0w = c0 + wid * 16;
    const int o = c0 >> (LW1 + 6);           // uniform per block (128 <= 64*2^LW1)

    // ---- stage ks0 slab (2688 f4) + H planes (5376 f4) ONCE ----
    {
        const char* g0 = (const char*)(Bg + (size_t)o * 21504);
        const char* gH = (const char*)(Bg + 1376256);
        char* l0 = (char*)B0;
        char* lH = (char*)BH;
        #pragma unroll
        for (int it = 0; it < 16; ++it) {
            const int base = it * 512 + wid * 64;     // float4 index, wave-uniform
            if (it == 15 && wid >= 6) break;          // 8064 total
            if (base < 2688) {
                gload_lds16(g0 + (size_t)(base + lane) * 16, l0 + (size_t)base * 16);
            } else {
                const int hb = base - 2688;
                gload_lds16(gH + (size_t)(hb + lane) * 16, lH + (size_t)hb * 16);
            }
        }
    }

    f32x4 acc[28];
    #pragma unroll
    for (int t = 0; t < 28; ++t) acc[t] = (f32x4){0.f, 0.f, 0.f, 0.f};

    // ---- phase-1 x A-frag + H A-prefetch (independent of LDS) ----
    bf16x8 axhi, axlo;
    {
        const int w = 1 << LW1;
        const int cm = c0w + j15;
        const int opm = cm >> LW1;
        const int nodem = w - 1 + (cm & (w - 1));
        const size_t nb = (size_t)opm * 63 + nodem;
        float xv0=0.f,xv1=0.f,xv2=0.f,xv3=0.f,xv4=0.f,xv5=0.f,xv6=0.f,xv7=0.f;
        if (qr == 0) {
            const float4* s4 = (const float4*)(samp + nb * 8);
            float4 a = s4[0], b = s4[1];
            xv0=a.x; xv1=a.y; xv2=a.z; xv3=a.w; xv4=b.x; xv5=b.y; xv6=b.z; xv7=b.w;
        } else if (qr == 1) {
            const float2* a2 = (const float2*)(addr + nb * 10);
            float2 e0=a2[0], e1=a2[1], e2=a2[2], e3=a2[3];
            xv0=e0.x; xv1=e0.y; xv2=e1.x; xv3=e1.y; xv4=e2.x; xv5=e2.y; xv6=e3.x; xv7=e3.y;
        } else if (qr == 2) {
            xv0 = addr[nb * 10 + 8]; xv1 = addr[nb * 10 + 9];
            xv2 = 1.0f;                          // bias row k=18
        }
        #define CVT(e, val) { unsigned short hh = f2bf(val); \
            axhi[e] = (short)hh; axlo[e] = (short)f2bf((val) - bf2f(hh)); }
        CVT(0, xv0) CVT(1, xv1) CVT(2, xv2) CVT(3, xv3)
        CVT(4, xv4) CVT(5, xv5) CVT(6, xv6) CVT(7, xv7)
        #undef CVT
    }
    bf16x8 ah1[4];
    if constexpr (!LEAF1) {
        const size_t arow = (size_t)(c0w + j15) * 128 + qr * 8;
        #pragma unroll
        for (int m = 0; m < 4; ++m)
            ah1[m] = *(const bf16x8*)(hin + arow + m * 32);
    }
    __syncthreads();   // barrier #1: slabs staged

    // ================= PHASE 1: all ksteps back-to-back =================
    #pragma unroll
    for (int s = 0; s < 21; ++s) {
        const unsigned short* bb = B0 + ((s * 4 + qr) * 16 + j15) * 8;
        bf16x8 bhi = *(const bf16x8*)bb;
        bf16x8 blo = *(const bf16x8*)(bb + 10752);
        acc[s] = __builtin_amdgcn_mfma_f32_16x16x32_bf16(axhi, bhi, acc[s], 0, 0, 0);
        acc[s] = __builtin_amdgcn_mfma_f32_16x16x32_bf16(axlo, bhi, acc[s], 0, 0, 0);
        acc[s] = __builtin_amdgcn_mfma_f32_16x16x32_bf16(axhi, blo, acc[s], 0, 0, 0);
    }
    if constexpr (!LEAF1) {
        #pragma unroll
        for (int ks = 1; ks <= 4; ++ks) {
            const unsigned short* hp = BH + (ks - 1) * 10752;
            #pragma unroll
            for (int s = 0; s < 21; ++s) {
                const int d = (s < 14) ? s : s + 7;
                bf16x8 bhi = *(const bf16x8*)(hp + ((s * 4 + qr) * 16 + j15) * 8);
                acc[d] = __builtin_amdgcn_mfma_f32_16x16x32_bf16(ah1[ks - 1], bhi, acc[d], 0, 0, 0);
            }
        }
    }

    // ---- phase-1 epilogue: gates + pairsum -> bf16 mid rows in LDS ----
    #pragma unroll
    for (int t = 0; t < 7; ++t) {
        const int u = t * 16 + j15;
        const float bh = (u < 100) ? bhh[200 + u] : 0.f;
        float hv0, hv1, hv2, hv3;
        #define GATE(reg, hvout) { \
            float rr = sigmoidf_(acc[t][reg]); \
            float zz = sigmoidf_(acc[t + 7][reg]); \
            float nn = tanhf_(acc[t + 14][reg] + rr * (acc[t + 21][reg] + bh)); \
            float hcv = 0.f; \
            if constexpr (!LEAF1) \
                hcv = bf2f(hin[(size_t)(c0w + qr * 4 + reg) * 128 + u]); \
            hvout = nn + zz * (hcv - nn); }
        GATE(0, hv0) GATE(1, hv1) GATE(2, hv2) GATE(3, hv3)
        #undef GATE
        const int r0 = wid * 8 + qr * 2;          // local mid row
        hmid[(r0)     * 136 + u] = f2bf(hv0 + hv1);
        hmid[(r0 + 1) * 136 + u] = f2bf(hv2 + hv3);
    }
    for (int f = tid; f < 1024; f += 512)
        hmid[(f >> 4) * 136 + 112 + (f & 15)] = 0;
    __syncthreads();   // barrier #2: hmid complete

    // ============ PHASE 2: level LW1-1, 64 cells, waves 0..3 ============
    {
        constexpr int LW2 = LW1 - 1;
        const int c20 = c0 >> 1;
        const int c2w = c20 + wid * 16;
        if (wid >= 4) return;               // no more barriers below

        #pragma unroll
        for (int t = 0; t < 28; ++t) acc[t] = (f32x4){0.f, 0.f, 0.f, 0.f};

        bf16x8 axhi2, axlo2;
        {
            const int w = 1 << LW2;
            const int cm = c2w + j15;
            const int opm = cm >> LW2;
            const int nodem = w - 1 + (cm & (w - 1));
            const size_t nb = (size_t)opm * 63 + nodem;
            float xv0=0.f,xv1=0.f,xv2=0.f,xv3=0.f,xv4=0.f,xv5=0.f,xv6=0.f,xv7=0.f;
            if (qr == 0) {
                const float4* s4 = (const float4*)(samp + nb * 8);
                float4 a = s4[0], b = s4[1];
                xv0=a.x; xv1=a.y; xv2=a.z; xv3=a.w; xv4=b.x; xv5=b.y; xv6=b.z; xv7=b.w;
            } else if (qr == 1) {
                const float2* a2 = (const float2*)(addr + nb * 10);
                float2 e0=a2[0], e1=a2[1], e2=a2[2], e3=a2[3];
                xv0=e0.x; xv1=e0.y; xv2=e1.x; xv3=e1.y; xv4=e2.x; xv5=e2.y; xv6=e3.x; xv7=e3.y;
            } else if (qr == 2) {
                xv0 = addr[nb * 10 + 8]; xv1 = addr[nb * 10 + 9];
                xv2 = 1.0f;
            }
            #define CVT(e, val) { unsigned short hh = f2bf(val); \
                axhi2[e] = (short)hh; axlo2[e] = (short)f2bf((val) - bf2f(hh)); }
            CVT(0, xv0) CVT(1, xv1) CVT(2, xv2) CVT(3, xv3)
            CVT(4, xv4) CVT(5, xv5) CVT(6, xv6) CVT(7, xv7)
            #undef CVT
        }

        #pragma unroll
        for (int s = 0; s < 21; ++s) {
            const unsigned short* bb = B0 + ((s * 4 + qr) * 16 + j15) * 8;
            bf16x8 bhi = *(const bf16x8*)bb;
            bf16x8 blo = *(const bf16x8*)(bb + 10752);
            acc[s] = __builtin_amdgcn_mfma_f32_16x16x32_bf16(axhi2, bhi, acc[s], 0, 0, 0);
            acc[s] = __builtin_amdgcn_mfma_f32_16x16x32_bf16(axlo2, bhi, acc[s], 0, 0, 0);
            acc[s] = __builtin_amdgcn_mfma_f32_16x16x32_bf16(axhi2, blo, acc[s], 0, 0, 0);
        }
        #pragma unroll
        for (int ks = 1; ks <= 4; ++ks) {
            bf16x8 ahi = *(const bf16x8*)(hmid + (wid * 16 + j15) * 136
                                               + (ks - 1) * 32 + qr * 8);
            const unsigned short* hp = BH + (ks - 1) * 10752;
            #pragma unroll
            for (int s = 0; s < 21; ++s) {
                const int d = (s < 14) ? s : s + 7;
                bf16x8 bhi = *(const bf16x8*)(hp + ((s * 4 + qr) * 16 + j15) * 8);
                acc[d] = __builtin_amdgcn_mfma_f32_16x16x32_bf16(ahi, bhi, acc[d], 0, 0, 0);
            }
        }

        #pragma unroll
        for (int t = 0; t < 7; ++t) {
            const int u = t * 16 + j15;
            const float bh = (u < 100) ? bhh[200 + u] : 0.f;
            float hv0, hv1, hv2, hv3;
            #define GATE(reg, hvout) { \
                float rr = sigmoidf_(acc[t][reg]); \
                float zz = sigmoidf_(acc[t + 7][reg]); \
                float nn = tanhf_(acc[t + 14][reg] + rr * (acc[t + 21][reg] + bh)); \
                float hcv = bf2f(hmid[(wid * 16 + qr * 4 + reg) * 136 + u]); \
                hvout = nn + zz * (hcv - nn); }
            GATE(0, hv0) GATE(1, hv1) GATE(2, hv2) GATE(3, hv3)
            #undef GATE
            if (LAST) {
                unsigned short* r0 = hout + (size_t)(c2w + qr * 4) * 128 + u;
                r0[0]   = f2bf(hv0);
                r0[128] = f2bf(hv1);
                r0[256] = f2bf(hv2);
                r0[384] = f2bf(hv3);
            } else {
                unsigned short* r0 = hout + (size_t)((c2w >> 1) + qr * 2) * 128 + u;
                r0[0]   = f2bf(hv0 + hv1);
                r0[128] = f2bf(hv2 + hv3);
            }
        }
        const int u2 = 112 + j15;
        if (LAST) {
            #pragma unroll
            for (int reg = 0; reg < 4; ++reg)
                hout[(size_t)(c2w + qr * 4 + reg) * 128 + u2] = 0;
        } else {
            #pragma unroll
            for (int p = 0; p < 2; ++p)
                hout[(size_t)((c2w >> 1) + qr * 2 + p) * 128 + u2] = 0;
        }
    }
}

// ---------------------------------------------------------------------------
// MLP head + logsumexp (bf16 h input — verified).
// ---------------------------------------------------------------------------
__global__ __launch_bounds__(256) void mlp_lse(
    const unsigned short* __restrict__ h0,  // [4096][128] bf16
    const float* __restrict__ W1T,  // [100][50]
    const float* __restrict__ b1,
    const float* __restrict__ W2T,  // [50][25]
    const float* __restrict__ b2,
    const float* __restrict__ W3,
    const float* __restrict__ b3,
    float* __restrict__ out)
{
    __shared__ float hs[64 * 101];
    __shared__ float w1s[5008];
    __shared__ float w2s[1250];
    __shared__ float y1s[64 * 50];

    const int o = blockIdx.x;
    const int tid = threadIdx.x;
    const int lane = tid & 63;
    const int wid = tid >> 6;

    for (int f = tid; f < 6400; f += 256) {
        int cl = f / 100, g = f - cl * 100;
        hs[cl * 101 + g] = bf2f(h0[(size_t)(o * 64 + cl) * 128 + g]);
    }
    for (int f = tid; f < 5000; f += 256) w1s[f] = W1T[f];
    for (int f = tid; f < 1250; f += 256) w2s[f] = W2T[f];
    __syncthreads();

    const int jbase = wid * 13;
    const int jn = (wid < 3) ? 13 : 11;       // 13+13+13+11 = 50
    float y1[13];
    #pragma unroll
    for (int jj = 0; jj < 13; ++jj) y1[jj] = b1[jbase + jj < 50 ? jbase + jj : 49];
    #pragma unroll 2
    for (int g = 0; g < 100; ++g) {
        float rg = hs[lane * 101 + g];
        const float* wr = w1s + g * 50 + jbase;
        #pragma unroll
        for (int jj = 0; jj < 13; ++jj) y1[jj] = fmaf(rg, wr[jj], y1[jj]);
    }
    #pragma unroll
    for (int jj = 0; jj < 13; ++jj)
        if (jj < jn) y1s[lane * 50 + jbase + jj] = y1[jj];
    __syncthreads();
    if (wid != 0) return;

    const int p = lane;
    float y2[25];
    #pragma unroll
    for (int i = 0; i < 25; ++i) y2[i] = b2[i];
    #pragma unroll 2
    for (int j = 0; j < 50; ++j) {
        float v = fmaxf(y1s[p * 50 + j], 0.0f);
        const float* wr = w2s + j * 25;
        #pragma unroll
        for (int i = 0; i < 25; ++i) y2[i] = fmaf(v, wr[i], y2[i]);
    }

    float cv = b3[0];
    #pragma unroll
    for (int i = 0; i < 25; ++i) cv = fmaf(fmaxf(y2[i], 0.0f), W3[i], cv);

    float m = cv;
    #pragma unroll
    for (int s = 1; s < 64; s <<= 1) m = fmaxf(m, __shfl_xor(m, s));
    float e = __expf(cv - m);
    #pragma unroll
    for (int s = 1; s < 64; s <<= 1) e += __shfl_xor(e, s);
    if (p == 0) out[o] = m + __logf(e) - 4.1588830833596715f; // log(64)
}

// ---------------------------------------------------------------------------
extern "C" void kernel_launch(void* const* d_in, const int* in_sizes, int n_in,
                              void* d_out, int out_size, void* d_ws, size_t ws_size,
                              hipStream_t stream)
{
    const float* obs  = (const float*)d_in[0];
    const float* samp = (const float*)d_in[1];
    const float* addr = (const float*)d_in[2];
    const float* W_ih = (const float*)d_in[3];
    const float* W_hh = (const float*)d_in[4];
    const float* b_ih = (const float*)d_in[5];
    const float* b_hh = (const float*)d_in[6];
    const float* W1   = (const float*)d_in[7];
    const float* b1   = (const float*)d_in[8];
    const float* W2   = (const float*)d_in[9];
    const float* b2   = (const float*)d_in[10];
    const float* W3   = (const float*)d_in[11];
    const float* b3   = (const float*)d_in[12];
    float* out = (float*)d_out;

    float* ws = (float*)d_ws;
    // Bg: 64*21504 + 4*10752 = 1419264 ush = 709632 floats
    unsigned short* Bg = (unsigned short*)ws;
    float* W1T = ws + 709632;                       // 5000
    float* W2T = ws + 714632;                       // 1250
    unsigned short* hU1 = (unsigned short*)(ws + 715888);   // 32768*128 ush
    unsigned short* hU2 = (unsigned short*)(ws + 2813040);  // 8192*128 ush
    unsigned short* hU3 = (unsigned short*)(ws + 3337328);  // 4096*128 ush

    const int DYN_LDS = 146432;  // 21504 + 43008 + 8704 ush = 73216 ush * 2 B
    (void)hipFuncSetAttribute((const void*)fused_pair<5, true, false>,
        hipFuncAttributeMaxDynamicSharedMemorySize, DYN_LDS);
    (void)hipFuncSetAttribute((const void*)fused_pair<3, false, false>,
        hipFuncAttributeMaxDynamicSharedMemorySize, DYN_LDS);
    (void)hipFuncSetAttribute((const void*)fused_pair<1, false, true>,
        hipFuncAttributeMaxDynamicSharedMemorySize, DYN_LDS);

    // threads: 688128 (ks0 slabs) + 43008 (H planes) + 5000 + 1250 = 737386
    precompute_kernel<<<(737386 + 63) / 64, 64, 0, stream>>>(
        obs, W_ih, W_hh, b_ih, b_hh, W1, W2, Bg, W1T, W2T);

    // pair A: leaf(lw=5) + L4 — 131072 cells -> 32768 rows (hU1)
    fused_pair<5, true, false><<<1024, 512, DYN_LDS, stream>>>(
        Bg, b_hh, samp, addr, nullptr, hU1);
    // pair B: L3 + L2 — 32768 cells (hU1) -> 8192 rows (hU2)
    fused_pair<3, false, false><<<256, 512, DYN_LDS, stream>>>(
        Bg, b_hh, samp, addr, hU1, hU2);
    // pair C: L1 + L0 — 8192 cells (hU2) -> 4096 rows (hU3), L0 = last
    fused_pair<1, false, true><<<64, 512, DYN_LDS, stream>>>(
        Bg, b_hh, samp, addr, hU2, hU3);

    mlp_lse<<<64, 256, 0, stream>>>(hU3, W1T, b1, W2T, b2, W3, b3, out);
}

// Round 21
// 132.667 us; speedup vs baseline: 1.9947x; 1.0560x over previous
//
#include <hip/hip_runtime.h>
#include <hip/hip_bf16.h>

typedef __attribute__((ext_vector_type(8))) short bf16x8;
typedef __attribute__((ext_vector_type(4))) float f32x4;

__device__ __forceinline__ float sigmoidf_(float x){ return 1.0f/(1.0f+__expf(-x)); }
__device__ __forceinline__ float tanhf_(float x){ return 1.0f - 2.0f/(1.0f+__expf(2.0f*x)); }
__device__ __forceinline__ unsigned short f2bf(float f){
    __hip_bfloat16 b = __float2bfloat16(f);
    return *reinterpret_cast<unsigned short*>(&b);
}
__device__ __forceinline__ float bf2f(unsigned short u){
    __hip_bfloat16 b = *reinterpret_cast<__hip_bfloat16*>(&u);
    return __bfloat162float(b);
}
// async global->LDS, 16B per lane; LDS dest = wave-uniform base (+lane*16 implicit)
__device__ __forceinline__ void gload_lds16(const void* gsrc, void* ldst){
    __builtin_amdgcn_global_load_lds(
        (const __attribute__((address_space(1))) unsigned int*)gsrc,
        (__attribute__((address_space(3))) unsigned int*)ldst,
        16, 0, 0);
}

// ---------------------------------------------------------------------------
// Layouts:
//  Bg (ushort):
//   X slabs 0..63 (per-o, SINGLE bf16 plane): 10752 ush = [21 slots][4 qr][16 j][8 e].
//     kk<18 -> bf16(W_ih[gate][100+kk]); kk==18 -> bf16(bias); kk==19 ->
//     bf16(bias - bf2f(bf16(bias))) (bias lo residual); kk>=20 -> 0.
//     bias = b_ih(+b_hh for r/z) + obs[o].W_ih[gate,:100] (fp32).
//     A supplies 1.0 at k=18 AND k=19 -> full-precision bias, zero init loads.
//   H planes (ks 1..4, single bf16 plane each): base 688128 + (ks-1)*10752.
//     Slots 0..13 -> tiles 0..13 (r,z); slots 14..20 -> tiles 21..27 (hn).
//     REGION 3 (hn) uses gate rows 200+u (same n-gate rows as region 2)!
//   Global H region padded to 43520 ush (= 5440 f4) for tail staging reads.
//  STAGING BYTE MATH (R19 bug: used 10752/16=672 — ushort count / 16!):
//   X slab  = 10752 ush * 2 B = 21504 B = 1344 float4
//   H slabs = 43520 ush * 2 B = 87040 B = 5440 float4
//   total staged = 6784 f4 = 13 rounds * 512 + 2 wave-chunks (wid<2)
//  h (bf16 ushort, global): [rows][128]; cols 100..127 are 0.
//  Dynamic LDS (125952 B = 62976 ush): B0 [0,10752) | BH [10752,54272)
//   (43520 incl. pad) | hmid [54272,62976) = [64 rows][136 ush].
//   hmid row stride MUST be a multiple of 8 ush (16 B) — ds_read_b128.
// ---------------------------------------------------------------------------
__global__ __launch_bounds__(64) void precompute_kernel(
    const float* __restrict__ obs, const float* __restrict__ W_ih,
    const float* __restrict__ W_hh, const float* __restrict__ b_ih,
    const float* __restrict__ b_hh, const float* __restrict__ W1,
    const float* __restrict__ W2,
    unsigned short* __restrict__ Bg,
    float* __restrict__ W1T, float* __restrict__ W2T)
{
    int t = blockIdx.x * 64 + threadIdx.x;
    if (t < 688128) { // X slabs, one per o: 64 * 10752 positions (single plane)
        int o = t / 10752, r = t % 10752;
        int s = r / 512, r2 = r % 512;
        int j = r2 / 32, kk = r2 % 32;
        int region = s / 7;                 // 0=r,1=z,2=i_n
        int u = (s % 7) * 16 + j;
        unsigned short outv = 0;
        if (u < 100) {
            int gate = region * 100 + u;
            if (kk < 18) {
                outv = f2bf(W_ih[(size_t)gate * 118 + 100 + kk]);
            } else if (kk == 18 || kk == 19) { // bias hi / lo rows
                float bias = b_ih[gate] + (region < 2 ? b_hh[gate] : 0.f);
                const float* orow = obs + o * 100;
                const float* wrow = W_ih + (size_t)gate * 118;
                for (int k = 0; k < 100; ++k) bias = fmaf(orow[k], wrow[k], bias);
                if (kk == 18) outv = f2bf(bias);
                else          outv = f2bf(bias - bf2f(f2bf(bias)));
            }
        }
        int qr = kk >> 3, e = kk & 7;
        Bg[(size_t)o * 10752 + (size_t)((s * 4 + qr) * 16 + j) * 8 + e] = outv;
        return;
    }
    t -= 688128;
    if (t < 43008) { // H planes (ks 1..4): 4 * 10752 positions, single bf16 plane
        int ks = 1 + t / 10752, r = t % 10752;
        int s = r / 512, r2 = r % 512;
        int j = r2 / 32, kk = r2 % 32;
        int tt = (s < 14) ? s : s + 7;
        int region = tt / 7;
        int u = (tt % 7) * 16 + j;
        float wv = 0.f;
        if (u < 100) {
            // region 3 (h_n) uses the SAME n-gate rows (200+u) as region 2
            int gate = (region == 3 ? 2 : region) * 100 + u;
            int kh = (ks - 1) * 32 + kk;
            if (kh < 100) wv = W_hh[(size_t)gate * 100 + kh];
        }
        int qr = kk >> 3, e = kk & 7;
        Bg[(size_t)688128 + (size_t)(ks - 1) * 10752
           + (size_t)((s * 4 + qr) * 16 + j) * 8 + e] = f2bf(wv);
        return;
    }
    t -= 43008;
    if (t < 512) { // zero the H pad tail [731136, 731648) so staging reads are defined
        Bg[731136 + t] = 0;
        return;
    }
    t -= 512;
    if (t < 5000) { int g = t / 50, j = t % 50; W1T[t] = W1[j * 100 + g]; return; }
    t -= 5000;
    if (t < 1250) { int j = t / 25, i = t % 25; W2T[t] = W2[i * 50 + j]; }
}

// ---------------------------------------------------------------------------
// FUSED level pair (LW1, LW1-1) — resident single-plane version. Block = 512
// thr (8 waves). X slab (21.5KB) + 4 H planes (86KB incl pad) staged ONCE into
// contiguous LDS (per-lane global src handles the X/H boundary; LDS dest
// linear). Phase 1 (128 cells, 8 waves) and phase 2 (64 cells, waves 0..3)
// run all ksteps back-to-back. 2 block barriers total.
// ks0: 2 MFMAs/slot (axhi,axlo vs single bhi). H: 1 MFMA/slot.
// ---------------------------------------------------------------------------
template<int LW1, bool LEAF1, bool LAST>
__global__ __launch_bounds__(512) void fused_pair(
    const unsigned short* __restrict__ Bg,
    const float* __restrict__ bhh,          // b_hh (for h_n bias rows 200+u)
    const float* __restrict__ samp,         // (O,P,63,8)
    const float* __restrict__ addr,         // (O,P,63,10)
    const unsigned short* __restrict__ hin, // [cellsIn][128] bf16 (unused if LEAF1)
    unsigned short* __restrict__ hout)      // [rowsOut][128] bf16
{
    extern __shared__ unsigned short smem[];
    unsigned short* B0   = smem;            // 10752 ush (single X plane)
    unsigned short* BH   = smem + 10752;    // 43520 ush (4 H planes + pad)
    unsigned short* hmid = smem + 54272;    // 8704 ush ([64][136], 16B-aligned rows)

    const int tid = threadIdx.x;
    const int lane = tid & 63;
    const int wid = tid >> 6;
    const int j15 = lane & 15;
    const int qr = lane >> 4;
    // XCD swizzle (grid % 8 == 0)
    const int wk = (blockIdx.x & 7) * (gridDim.x >> 3) + (blockIdx.x >> 3);
    const int c0 = wk * 128;                 // first phase-1 cell
    const int c0w = c0 + wid * 16;
    const int o = c0 >> (LW1 + 6);           // uniform per block (128 <= 64*2^LW1)

    // ---- stage X slab (1344 f4) + H planes (5440 f4) ONCE: 6784 f4 total ----
    // X slab = 10752 ush * 2B / 16B = 1344 f4  (NOT 10752/16 — R19's bug!)
    {
        const char* g0 = (const char*)(Bg + (size_t)o * 10752);
        const char* gH = (const char*)(Bg + 688128);
        char* l0 = (char*)smem;
        #pragma unroll
        for (int it = 0; it < 13; ++it) {
            const int base = it * 512 + wid * 64;      // f4 index, wave-uniform
            const int fi = base + lane;                // per-lane f4 index
            const char* src = (fi < 1344) ? g0 + (size_t)fi * 16
                                          : gH + (size_t)(fi - 1344) * 16;
            gload_lds16(src, l0 + (size_t)base * 16);
        }
        if (wid < 2) {                                 // tail: 6784-6656=128 f4
            const int base = 6656 + wid * 64;
            const int fi = base + lane;                // all >= 1344 -> H source
            gload_lds16(gH + (size_t)(fi - 1344) * 16, l0 + (size_t)base * 16);
        }
    }

    f32x4 acc[28];
    #pragma unroll
    for (int t = 0; t < 28; ++t) acc[t] = (f32x4){0.f, 0.f, 0.f, 0.f};

    // ---- phase-1 x A-frag + H A-prefetch (independent of LDS) ----
    bf16x8 axhi, axlo;
    {
        const int w = 1 << LW1;
        const int cm = c0w + j15;
        const int opm = cm >> LW1;
        const int nodem = w - 1 + (cm & (w - 1));
        const size_t nb = (size_t)opm * 63 + nodem;
        float xv0=0.f,xv1=0.f,xv2=0.f,xv3=0.f,xv4=0.f,xv5=0.f,xv6=0.f,xv7=0.f;
        if (qr == 0) {
            const float4* s4 = (const float4*)(samp + nb * 8);
            float4 a = s4[0], b = s4[1];
            xv0=a.x; xv1=a.y; xv2=a.z; xv3=a.w; xv4=b.x; xv5=b.y; xv6=b.z; xv7=b.w;
        } else if (qr == 1) {
            const float2* a2 = (const float2*)(addr + nb * 10);
            float2 e0=a2[0], e1=a2[1], e2=a2[2], e3=a2[3];
            xv0=e0.x; xv1=e0.y; xv2=e1.x; xv3=e1.y; xv4=e2.x; xv5=e2.y; xv6=e3.x; xv7=e3.y;
        } else if (qr == 2) {
            xv0 = addr[nb * 10 + 8]; xv1 = addr[nb * 10 + 9];
            xv2 = 1.0f;                          // bias hi row k=18
            xv3 = 1.0f;                          // bias lo row k=19
        }
        #define CVT(e, val) { unsigned short hh = f2bf(val); \
            axhi[e] = (short)hh; axlo[e] = (short)f2bf((val) - bf2f(hh)); }
        CVT(0, xv0) CVT(1, xv1) CVT(2, xv2) CVT(3, xv3)
        CVT(4, xv4) CVT(5, xv5) CVT(6, xv6) CVT(7, xv7)
        #undef CVT
    }
    bf16x8 ah1[4];
    if constexpr (!LEAF1) {
        const size_t arow = (size_t)(c0w + j15) * 128 + qr * 8;
        #pragma unroll
        for (int m = 0; m < 4; ++m)
            ah1[m] = *(const bf16x8*)(hin + arow + m * 32);
    }
    __syncthreads();   // barrier #1: slabs staged

    // ================= PHASE 1: all ksteps back-to-back =================
    #pragma unroll
    for (int s = 0; s < 21; ++s) {
        bf16x8 bhi = *(const bf16x8*)(B0 + ((s * 4 + qr) * 16 + j15) * 8);
        acc[s] = __builtin_amdgcn_mfma_f32_16x16x32_bf16(axhi, bhi, acc[s], 0, 0, 0);
        acc[s] = __builtin_amdgcn_mfma_f32_16x16x32_bf16(axlo, bhi, acc[s], 0, 0, 0);
    }
    if constexpr (!LEAF1) {
        #pragma unroll
        for (int ks = 1; ks <= 4; ++ks) {
            const unsigned short* hp = BH + (ks - 1) * 10752;
            #pragma unroll
            for (int s = 0; s < 21; ++s) {
                const int d = (s < 14) ? s : s + 7;
                bf16x8 bhi = *(const bf16x8*)(hp + ((s * 4 + qr) * 16 + j15) * 8);
                acc[d] = __builtin_amdgcn_mfma_f32_16x16x32_bf16(ah1[ks - 1], bhi, acc[d], 0, 0, 0);
            }
        }
    }

    // ---- phase-1 epilogue: gates + pairsum -> bf16 mid rows in LDS ----
    #pragma unroll
    for (int t = 0; t < 7; ++t) {
        const int u = t * 16 + j15;
        const float bh = (u < 100) ? bhh[200 + u] : 0.f;
        float hv0, hv1, hv2, hv3;
        #define GATE(reg, hvout) { \
            float rr = sigmoidf_(acc[t][reg]); \
            float zz = sigmoidf_(acc[t + 7][reg]); \
            float nn = tanhf_(acc[t + 14][reg] + rr * (acc[t + 21][reg] + bh)); \
            float hcv = 0.f; \
            if constexpr (!LEAF1) \
                hcv = bf2f(hin[(size_t)(c0w + qr * 4 + reg) * 128 + u]); \
            hvout = nn + zz * (hcv - nn); }
        GATE(0, hv0) GATE(1, hv1) GATE(2, hv2) GATE(3, hv3)
        #undef GATE
        const int r0 = wid * 8 + qr * 2;          // local mid row
        hmid[(r0)     * 136 + u] = f2bf(hv0 + hv1);
        hmid[(r0 + 1) * 136 + u] = f2bf(hv2 + hv3);
    }
    for (int f = tid; f < 1024; f += 512)
        hmid[(f >> 4) * 136 + 112 + (f & 15)] = 0;
    __syncthreads();   // barrier #2: hmid complete

    // ============ PHASE 2: level LW1-1, 64 cells, waves 0..3 ============
    {
        constexpr int LW2 = LW1 - 1;
        const int c20 = c0 >> 1;
        const int c2w = c20 + wid * 16;
        if (wid >= 4) return;               // no more barriers below

        #pragma unroll
        for (int t = 0; t < 28; ++t) acc[t] = (f32x4){0.f, 0.f, 0.f, 0.f};

        bf16x8 axhi2, axlo2;
        {
            const int w = 1 << LW2;
            const int cm = c2w + j15;
            const int opm = cm >> LW2;
            const int nodem = w - 1 + (cm & (w - 1));
            const size_t nb = (size_t)opm * 63 + nodem;
            float xv0=0.f,xv1=0.f,xv2=0.f,xv3=0.f,xv4=0.f,xv5=0.f,xv6=0.f,xv7=0.f;
            if (qr == 0) {
                const float4* s4 = (const float4*)(samp + nb * 8);
                float4 a = s4[0], b = s4[1];
                xv0=a.x; xv1=a.y; xv2=a.z; xv3=a.w; xv4=b.x; xv5=b.y; xv6=b.z; xv7=b.w;
            } else if (qr == 1) {
                const float2* a2 = (const float2*)(addr + nb * 10);
                float2 e0=a2[0], e1=a2[1], e2=a2[2], e3=a2[3];
                xv0=e0.x; xv1=e0.y; xv2=e1.x; xv3=e1.y; xv4=e2.x; xv5=e2.y; xv6=e3.x; xv7=e3.y;
            } else if (qr == 2) {
                xv0 = addr[nb * 10 + 8]; xv1 = addr[nb * 10 + 9];
                xv2 = 1.0f;
                xv3 = 1.0f;
            }
            #define CVT(e, val) { unsigned short hh = f2bf(val); \
                axhi2[e] = (short)hh; axlo2[e] = (short)f2bf((val) - bf2f(hh)); }
            CVT(0, xv0) CVT(1, xv1) CVT(2, xv2) CVT(3, xv3)
            CVT(4, xv4) CVT(5, xv5) CVT(6, xv6) CVT(7, xv7)
            #undef CVT
        }

        #pragma unroll
        for (int s = 0; s < 21; ++s) {
            bf16x8 bhi = *(const bf16x8*)(B0 + ((s * 4 + qr) * 16 + j15) * 8);
            acc[s] = __builtin_amdgcn_mfma_f32_16x16x32_bf16(axhi2, bhi, acc[s], 0, 0, 0);
            acc[s] = __builtin_amdgcn_mfma_f32_16x16x32_bf16(axlo2, bhi, acc[s], 0, 0, 0);
        }
        #pragma unroll
        for (int ks = 1; ks <= 4; ++ks) {
            bf16x8 ahi = *(const bf16x8*)(hmid + (wid * 16 + j15) * 136
                                               + (ks - 1) * 32 + qr * 8);
            const unsigned short* hp = BH + (ks - 1) * 10752;
            #pragma unroll
            for (int s = 0; s < 21; ++s) {
                const int d = (s < 14) ? s : s + 7;
                bf16x8 bhi = *(const bf16x8*)(hp + ((s * 4 + qr) * 16 + j15) * 8);
                acc[d] = __builtin_amdgcn_mfma_f32_16x16x32_bf16(ahi, bhi, acc[d], 0, 0, 0);
            }
        }

        #pragma unroll
        for (int t = 0; t < 7; ++t) {
            const int u = t * 16 + j15;
            const float bh = (u < 100) ? bhh[200 + u] : 0.f;
            float hv0, hv1, hv2, hv3;
            #define GATE(reg, hvout) { \
                float rr = sigmoidf_(acc[t][reg]); \
                float zz = sigmoidf_(acc[t + 7][reg]); \
                float nn = tanhf_(acc[t + 14][reg] + rr * (acc[t + 21][reg] + bh)); \
                float hcv = bf2f(hmid[(wid * 16 + qr * 4 + reg) * 136 + u]); \
                hvout = nn + zz * (hcv - nn); }
            GATE(0, hv0) GATE(1, hv1) GATE(2, hv2) GATE(3, hv3)
            #undef GATE
            if (LAST) {
                unsigned short* r0 = hout + (size_t)(c2w + qr * 4) * 128 + u;
                r0[0]   = f2bf(hv0);
                r0[128] = f2bf(hv1);
                r0[256] = f2bf(hv2);
                r0[384] = f2bf(hv3);
            } else {
                unsigned short* r0 = hout + (size_t)((c2w >> 1) + qr * 2) * 128 + u;
                r0[0]   = f2bf(hv0 + hv1);
                r0[128] = f2bf(hv2 + hv3);
            }
        }
        const int u2 = 112 + j15;
        if (LAST) {
            #pragma unroll
            for (int reg = 0; reg < 4; ++reg)
                hout[(size_t)(c2w + qr * 4 + reg) * 128 + u2] = 0;
        } else {
            #pragma unroll
            for (int p = 0; p < 2; ++p)
                hout[(size_t)((c2w >> 1) + qr * 2 + p) * 128 + u2] = 0;
        }
    }
}

// ---------------------------------------------------------------------------
// MLP head + logsumexp (bf16 h input — verified).
// ---------------------------------------------------------------------------
__global__ __launch_bounds__(256) void mlp_lse(
    const unsigned short* __restrict__ h0,  // [4096][128] bf16
    const float* __restrict__ W1T,  // [100][50]
    const float* __restrict__ b1,
    const float* __restrict__ W2T,  // [50][25]
    const float* __restrict__ b2,
    const float* __restrict__ W3,
    const float* __restrict__ b3,
    float* __restrict__ out)
{
    __shared__ float hs[64 * 101];
    __shared__ float w1s[5008];
    __shared__ float w2s[1250];
    __shared__ float y1s[64 * 50];

    const int o = blockIdx.x;
    const int tid = threadIdx.x;
    const int lane = tid & 63;
    const int wid = tid >> 6;

    for (int f = tid; f < 6400; f += 256) {
        int cl = f / 100, g = f - cl * 100;
        hs[cl * 101 + g] = bf2f(h0[(size_t)(o * 64 + cl) * 128 + g]);
    }
    for (int f = tid; f < 5000; f += 256) w1s[f] = W1T[f];
    for (int f = tid; f < 1250; f += 256) w2s[f] = W2T[f];
    __syncthreads();

    const int jbase = wid * 13;
    const int jn = (wid < 3) ? 13 : 11;       // 13+13+13+11 = 50
    float y1[13];
    #pragma unroll
    for (int jj = 0; jj < 13; ++jj) y1[jj] = b1[jbase + jj < 50 ? jbase + jj : 49];
    #pragma unroll 2
    for (int g = 0; g < 100; ++g) {
        float rg = hs[lane * 101 + g];
        const float* wr = w1s + g * 50 + jbase;
        #pragma unroll
        for (int jj = 0; jj < 13; ++jj) y1[jj] = fmaf(rg, wr[jj], y1[jj]);
    }
    #pragma unroll
    for (int jj = 0; jj < 13; ++jj)
        if (jj < jn) y1s[lane * 50 + jbase + jj] = y1[jj];
    __syncthreads();
    if (wid != 0) return;

    const int p = lane;
    float y2[25];
    #pragma unroll
    for (int i = 0; i < 25; ++i) y2[i] = b2[i];
    #pragma unroll 2
    for (int j = 0; j < 50; ++j) {
        float v = fmaxf(y1s[p * 50 + j], 0.0f);
        const float* wr = w2s + j * 25;
        #pragma unroll
        for (int i = 0; i < 25; ++i) y2[i] = fmaf(v, wr[i], y2[i]);
    }

    float cv = b3[0];
    #pragma unroll
    for (int i = 0; i < 25; ++i) cv = fmaf(fmaxf(y2[i], 0.0f), W3[i], cv);

    float m = cv;
    #pragma unroll
    for (int s = 1; s < 64; s <<= 1) m = fmaxf(m, __shfl_xor(m, s));
    float e = __expf(cv - m);
    #pragma unroll
    for (int s = 1; s < 64; s <<= 1) e += __shfl_xor(e, s);
    if (p == 0) out[o] = m + __logf(e) - 4.1588830833596715f; // log(64)
}

// ---------------------------------------------------------------------------
extern "C" void kernel_launch(void* const* d_in, const int* in_sizes, int n_in,
                              void* d_out, int out_size, void* d_ws, size_t ws_size,
                              hipStream_t stream)
{
    const float* obs  = (const float*)d_in[0];
    const float* samp = (const float*)d_in[1];
    const float* addr = (const float*)d_in[2];
    const float* W_ih = (const float*)d_in[3];
    const float* W_hh = (const float*)d_in[4];
    const float* b_ih = (const float*)d_in[5];
    const float* b_hh = (const float*)d_in[6];
    const float* W1   = (const float*)d_in[7];
    const float* b1   = (const float*)d_in[8];
    const float* W2   = (const float*)d_in[9];
    const float* b2   = (const float*)d_in[10];
    const float* W3   = (const float*)d_in[11];
    const float* b3   = (const float*)d_in[12];
    float* out = (float*)d_out;

    float* ws = (float*)d_ws;
    // Bg: 64*10752 (X) + 43520 (H incl 512-ush pad) = 731648 ush = 365824 floats
    unsigned short* Bg = (unsigned short*)ws;
    float* W1T = ws + 365824;                       // 5000
    float* W2T = ws + 370824;                       // 1250
    unsigned short* hU1 = (unsigned short*)(ws + 372080);   // 32768*128 ush
    unsigned short* hU2 = (unsigned short*)(ws + 2469232);  // 8192*128 ush
    unsigned short* hU3 = (unsigned short*)(ws + 2993520);  // 4096*128 ush

    const int DYN_LDS = 125952;  // (10752 + 43520 + 8704) ush * 2 B
    (void)hipFuncSetAttribute((const void*)fused_pair<5, true, false>,
        hipFuncAttributeMaxDynamicSharedMemorySize, DYN_LDS);
    (void)hipFuncSetAttribute((const void*)fused_pair<3, false, false>,
        hipFuncAttributeMaxDynamicSharedMemorySize, DYN_LDS);
    (void)hipFuncSetAttribute((const void*)fused_pair<1, false, true>,
        hipFuncAttributeMaxDynamicSharedMemorySize, DYN_LDS);

    // threads: 688128 (X) + 43008 (H) + 512 (H pad zero) + 5000 + 1250 = 737898
    precompute_kernel<<<(737898 + 63) / 64, 64, 0, stream>>>(
        obs, W_ih, W_hh, b_ih, b_hh, W1, W2, Bg, W1T, W2T);

    // pair A: leaf(lw=5) + L4 — 131072 cells -> 32768 rows (hU1)
    fused_pair<5, true, false><<<1024, 512, DYN_LDS, stream>>>(
        Bg, b_hh, samp, addr, nullptr, hU1);
    // pair B: L3 + L2 — 32768 cells (hU1) -> 8192 rows (hU2)
    fused_pair<3, false, false><<<256, 512, DYN_LDS, stream>>>(
        Bg, b_hh, samp, addr, hU1, hU2);
    // pair C: L1 + L0 — 8192 cells (hU2) -> 4096 rows (hU3), L0 = last
    fused_pair<1, false, true><<<64, 512, DYN_LDS, stream>>>(
        Bg, b_hh, samp, addr, hU2, hU3);

    mlp_lse<<<64, 256, 0, stream>>>(hU3, W1T, b1, W2T, b2, W3, b3, out);
}